// Round 3
// baseline (558.958 us; speedup 1.0000x reference)
//
#include <hip/hip_runtime.h>
#include <hip/hip_bf16.h>
#include <math.h>

// DenseGCN3Layer on MI355X — round 11.
// Changes vs r10:
//  * Dispatch graph restructured 13 -> 9 kernels:
//      memset -> FKA{prep ∥ hist+deg} -> FKS{scan ∥ dinv} ->
//      FKB{partition ∥ gemm0} -> csr -> agg64+gemm1 -> agg32+gemm2 -> agg16.
//  * Node degrees via global atomics in the hist pass; dinv computed in the
//    scan dispatch => gemm0 no longer depends on csr_build => gemm0 overlaps
//    partition in one fat kernel (LDS union 41KB, P1_CHUNK 8192->4096).
//  * gemm1 folded into agg<64> epilogue (64->48 matvec on reduced f32 regs,
//    writes g2 + pre3 RMW); gemm2 folded into agg<32> epilogue (32->16).
//    x1/x2 never materialized.
//  * agg main gather loop unchanged from r10 (it is LLC-bound, not VALU).

#define NBUCK_MAX 512
#define P1_CHUNK 4096
#define EPT 16
#define BCAP 9216
#define PREP_BLOCKS 142
#define HIST_BLOCKS 1024

typedef __attribute__((ext_vector_type(8))) short bfrag;   // 8 bf16 (4 VGPR)
typedef __attribute__((ext_vector_type(4))) float f4_t;    // acc
typedef __attribute__((ext_vector_type(2))) float f2_t;    // packed pair

__device__ inline float uaf(unsigned u) { return __uint_as_float(u); }
__device__ inline ushort f2bf(float f) {
    __hip_bfloat16 b = __float2bfloat16(f);
    return *reinterpret_cast<ushort*>(&b);
}
__device__ inline bfrag cvt8(const float4 a, const float4 b) {
    union { ushort u[8]; bfrag f; } r;
    r.u[0] = f2bf(a.x); r.u[1] = f2bf(a.y); r.u[2] = f2bf(a.z); r.u[3] = f2bf(a.w);
    r.u[4] = f2bf(b.x); r.u[5] = f2bf(b.y); r.u[6] = f2bf(b.z); r.u[7] = f2bf(b.w);
    return r.f;
}
__device__ inline bfrag ld_bfrag(const ushort* p) {
    const uint4 raw = *reinterpret_cast<const uint4*>(p);
    return *reinterpret_cast<const bfrag*>(&raw);
}

// ------------------------------------------------ FKA: prep ∥ hist+deg

__global__ __launch_bounds__(256) void fka_kernel(
    const float* __restrict__ W1, const float* __restrict__ Ws02,
    const float* __restrict__ Ws03, const float* __restrict__ W2,
    const float* __restrict__ Ws13, const float* __restrict__ W3,
    ushort* __restrict__ Wt0, ushort* __restrict__ Wt1, ushort* __restrict__ Wt2,
    const int* __restrict__ dst, int E, int* __restrict__ bucket_count,
    int* __restrict__ deg, int nbuckets)
{
    if (blockIdx.x < PREP_BLOCKS) {
        const int idx = blockIdx.x * 256 + threadIdx.x;
        if (idx < 32768) {
            int f = idx >> 8, k = idx & 255;
            float v = 0.f;
            if (f < 64)       v = W1[k * 64 + f];
            else if (f < 96)  v = Ws02[k * 32 + (f - 64)];
            else if (f < 112) v = Ws03[k * 16 + (f - 96)];
            Wt0[idx] = f2bf(v);
        } else if (idx < 32768 + 3072) {
            int t = idx - 32768;
            int f = t >> 6, k = t & 63;
            float v = (f < 32) ? W2[k * 32 + f] : Ws13[k * 16 + (f - 32)];
            Wt1[t] = f2bf(v);
        } else if (idx < 32768 + 3072 + 512) {
            int t = idx - 32768 - 3072;
            int f = t >> 5, k = t & 31;
            Wt2[t] = f2bf(W3[k * 16 + f]);
        }
        return;
    }
    // hist + degree role
    __shared__ int lhist[NBUCK_MAX];
    const int bid = blockIdx.x - PREP_BLOCKS;
    for (int i = threadIdx.x; i < nbuckets; i += 256) lhist[i] = 0;
    __syncthreads();
    const int stride = HIST_BLOCKS * 256;
    for (int e = bid * 256 + threadIdx.x; e < E; e += stride) {
        const int d = dst[e];
        atomicAdd(&lhist[d >> 8], 1);
        atomicAdd(&deg[d], 1);
    }
    __syncthreads();
    for (int i = threadIdx.x; i < nbuckets; i += 256) {
        int c = lhist[i];
        if (c) atomicAdd(&bucket_count[i], c);
    }
}

// ------------------------------------------------ FKS: scan ∥ dinv

__global__ __launch_bounds__(512) void fks_kernel(
    const int* __restrict__ bucket_count, int* __restrict__ bucket_base,
    int* __restrict__ bucket_cursor, const int* __restrict__ deg,
    float* __restrict__ dinv, int nbuckets, int N)
{
    if (blockIdx.x != 0) {
        const int i = (blockIdx.x - 1) * 512 + threadIdx.x;
        if (i < N) dinv[i] = rsqrtf((float)deg[i] + 1.0f);
        return;
    }
    __shared__ int tmp[512];
    const int tid = threadIdx.x;
    int v = (tid < nbuckets) ? bucket_count[tid] : 0;
    tmp[tid] = v;
    __syncthreads();
    for (int off = 1; off < 512; off <<= 1) {
        int t = (tid >= off) ? tmp[tid - off] : 0;
        __syncthreads();
        tmp[tid] += t;
        __syncthreads();
    }
    if (tid < nbuckets) {
        int base = tmp[tid] - v;
        bucket_base[tid]   = base;
        bucket_cursor[tid] = base;
    }
}

// ------------------------------------------------ FKB: partition ∥ gemm0

union FKBsh {
    float xs[2][4096];                       // gemm0: 2 x 16 KB
    struct {
        int hist[NBUCK_MAX];
        int lofs[NBUCK_MAX];
        int gbase[NBUCK_MAX];
        int lcur[NBUCK_MAX];
        int ssum[256];
        unsigned int stage[P1_CHUNK];
        int gidx[P1_CHUNK];
    } p;                                     // partition: ~41 KB
};

__global__ __launch_bounds__(256, 3) void fkb_kernel(
    // partition role
    const int* __restrict__ src, const int* __restrict__ dst, int E,
    int* __restrict__ bucket_cursor, unsigned int* __restrict__ keys,
    int nbuckets, int part_blocks,
    // gemm0 role
    const float* __restrict__ X, const ushort* __restrict__ Wt0,
    const float* __restrict__ bs02, const float* __restrict__ bs03,
    const float* __restrict__ dinv, ushort* __restrict__ g1,
    float* __restrict__ pre2, float* __restrict__ pre3, int N)
{
    __shared__ __align__(16) FKBsh sh;
    const int tid = threadIdx.x;

    if (blockIdx.x < part_blocks) {
        // ---------------- partition role ----------------
        const int e0 = blockIdx.x * P1_CHUNK;
        const int nE = min(P1_CHUNK, E - e0);

        for (int i = tid; i < NBUCK_MAX; i += 256) { sh.p.hist[i] = 0; sh.p.lcur[i] = 0; }
        __syncthreads();

        int myb[EPT];
        unsigned int mypk[EPT];
#pragma unroll
        for (int j = 0; j < EPT; ++j) {
            const int e = e0 + tid + j * 256;
            if (e < E) {
                const int d = dst[e];
                myb[j]  = d >> 8;
                mypk[j] = ((unsigned int)(d & 255) << 17) | (unsigned int)src[e];
                atomicAdd(&sh.p.hist[myb[j]], 1);
            } else myb[j] = -1;
        }
        __syncthreads();

        int a0 = (2 * tid     < nbuckets) ? sh.p.hist[2 * tid]     : 0;
        int a1 = (2 * tid + 1 < nbuckets) ? sh.p.hist[2 * tid + 1] : 0;
        sh.p.ssum[tid] = a0 + a1;
        __syncthreads();
        for (int off = 1; off < 256; off <<= 1) {
            int t = (tid >= off) ? sh.p.ssum[tid - off] : 0;
            __syncthreads();
            sh.p.ssum[tid] += t;
            __syncthreads();
        }
        const int ex = sh.p.ssum[tid] - (a0 + a1);
        if (2 * tid     < nbuckets) sh.p.lofs[2 * tid]     = ex;
        if (2 * tid + 1 < nbuckets) sh.p.lofs[2 * tid + 1] = ex + a0;
        __syncthreads();

        for (int i = tid; i < nbuckets; i += 256)
            sh.p.gbase[i] = atomicAdd(&bucket_cursor[i], sh.p.hist[i]);
        __syncthreads();

#pragma unroll
        for (int j = 0; j < EPT; ++j) {
            if (myb[j] >= 0) {
                const int b = myb[j];
                const int l = sh.p.lofs[b] + atomicAdd(&sh.p.lcur[b], 1);
                sh.p.stage[l] = mypk[j];
                sh.p.gidx[l]  = sh.p.gbase[b] - sh.p.lofs[b] + l;
            }
        }
        __syncthreads();

        for (int i = tid; i < nE; i += 256)
            keys[sh.p.gidx[i]] = sh.p.stage[i];
        return;
    }

    // ---------------- gemm0 role ----------------
    const int bid  = blockIdx.x - part_blocks;
    const int lane = tid & 63;
    const int wf   = tid >> 6;
    const int n0   = bid * 64;
    const int mrow = lane & 15;
    const int q    = lane >> 4;
    const int kq   = q * 8;

    bfrag bfr[2][8];
#pragma unroll
    for (int ft = 0; ft < 2; ++ft) {
        const ushort* wr = &Wt0[(size_t)(wf * 32 + ft * 16 + mrow) * 256 + kq];
#pragma unroll
        for (int p = 0; p < 8; ++p)
            bfr[ft][p] = ld_bfrag(&wr[p * 32]);
    }

    int srow[4], schunk[4];
#pragma unroll
    for (int j = 0; j < 4; ++j) {
        const int R = wf * 16 + j * 4 + q;
        srow[j]   = min(n0 + R, N - 1);
        schunk[j] = mrow ^ (R & 7);
    }

    auto STAGE = [&](int buf, int kc) {
#pragma unroll
        for (int j = 0; j < 4; ++j) {
            const float* gsrc =
                X + (size_t)srow[j] * 256 + kc * 64 + schunk[j] * 4;
            __builtin_amdgcn_global_load_lds(
                (const __attribute__((address_space(1))) unsigned int*)gsrc,
                (__attribute__((address_space(3))) unsigned int*)
                    &sh.xs[buf][(wf * 16 + j * 4) * 64],
                16, 0, 0);
        }
    };

    f4_t acc[4][2];
#pragma unroll
    for (int a = 0; a < 4; ++a)
#pragma unroll
        for (int b = 0; b < 2; ++b) acc[a][b] = {0.f, 0.f, 0.f, 0.f};

    STAGE(0, 0);
    __syncthreads();

    int cur = 0;
    for (int kc = 0; kc < 4; ++kc) {
        if (kc < 3) STAGE(cur ^ 1, kc + 1);
        const float4* Xs4 = reinterpret_cast<const float4*>(&sh.xs[cur][0]);
#pragma unroll
        for (int pl = 0; pl < 2; ++pl) {
            bfrag af[4];
#pragma unroll
            for (int mt = 0; mt < 4; ++mt) {
                const int r  = mt * 16 + mrow;
                const int c0 = pl * 8 + q * 2;
                const float4 u0 = Xs4[r * 16 + (c0 ^ (r & 7))];
                const float4 u1 = Xs4[r * 16 + ((c0 + 1) ^ (r & 7))];
                af[mt] = cvt8(u0, u1);
            }
            const int pg = kc * 2 + pl;
#pragma unroll
            for (int mt = 0; mt < 4; ++mt)
#pragma unroll
                for (int ft = 0; ft < 2; ++ft)
                    acc[mt][ft] = __builtin_amdgcn_mfma_f32_16x16x32_bf16(
                        af[mt], bfr[ft][pg], acc[mt][ft], 0, 0, 0);
        }
        __syncthreads();
        cur ^= 1;
    }

    // staged epilogue (reuses LDS)
    char* sm = (char*)&sh;
    ushort* g1s = (ushort*)sm;                   // [64][64]  8 KB
    float*  p2s = (float*)(sm + 8192);           // [64][32]  8 KB
    float*  p3s = (float*)(sm + 16384);          // [64][16]  4 KB

    if (wf < 2) {
#pragma unroll
        for (int mt = 0; mt < 4; ++mt) {
#pragma unroll
            for (int r = 0; r < 4; ++r) {
                const int nl = mt * 16 + q * 4 + r;
                const float di = dinv[min(n0 + nl, N - 1)];
#pragma unroll
                for (int ft = 0; ft < 2; ++ft)
                    g1s[nl * 64 + wf * 32 + ft * 16 + mrow] =
                        f2bf(di * acc[mt][ft][r]);
            }
        }
    } else if (wf == 2) {
#pragma unroll
        for (int mt = 0; mt < 4; ++mt)
#pragma unroll
            for (int ft = 0; ft < 2; ++ft)
#pragma unroll
                for (int r = 0; r < 4; ++r)
                    p2s[(mt * 16 + q * 4 + r) * 32 + ft * 16 + mrow] =
                        acc[mt][ft][r] + bs02[ft * 16 + mrow];
    } else {
#pragma unroll
        for (int mt = 0; mt < 4; ++mt)
#pragma unroll
            for (int r = 0; r < 4; ++r)
                p3s[(mt * 16 + q * 4 + r) * 16 + mrow] =
                    acc[mt][0][r] + bs03[mrow];
    }
    __syncthreads();

    const uint4* g1v = (const uint4*)g1s;
    const uint4* p2v = (const uint4*)p2s;
    const uint4* p3v = (const uint4*)p3s;
#pragma unroll
    for (int t = 0; t < 2; ++t) {
        const int i   = t * 256 + tid;
        const int row = i >> 3;
        if (n0 + row < N)
            *(uint4*)(g1 + (size_t)(n0 + row) * 64 + (i & 7) * 8) = g1v[i];
    }
#pragma unroll
    for (int t = 0; t < 2; ++t) {
        const int i   = t * 256 + tid;
        const int row = i >> 3;
        if (n0 + row < N)
            *(uint4*)(pre2 + (size_t)(n0 + row) * 32 + (i & 7) * 4) = p2v[i];
    }
    {
        const int i   = tid;
        const int row = i >> 2;
        if (n0 + row < N)
            *(uint4*)(pre3 + (size_t)(n0 + row) * 16 + (i & 3) * 4) = p3v[i];
    }
}

// ------------------------------------------------ csr build (dinv removed)

__global__ __launch_bounds__(256) void csr_build_kernel(
    const unsigned int* __restrict__ keys, const int* __restrict__ bucket_base,
    const int* __restrict__ bucket_count,
    int* __restrict__ row_off, int* __restrict__ col, int N, int E)
{
    __shared__ unsigned int inb[BCAP];
    __shared__ int outv[BCAP];
    __shared__ int hist[256];
    __shared__ int lofs[256];
    __shared__ int ssum[256];

    const int tid  = threadIdx.x;
    const int b    = blockIdx.x;
    const int base = bucket_base[b];
    const int cnt  = min(bucket_count[b], BCAP);
    const int n0   = b << 8;
    const int nn   = min(256, N - n0);

    for (int i = tid; i < cnt; i += 256) inb[i] = keys[base + i];
    hist[tid] = 0;
    __syncthreads();

    for (int i = tid; i < cnt; i += 256)
        atomicAdd(&hist[inb[i] >> 17], 1);
    __syncthreads();

    ssum[tid] = hist[tid];
    __syncthreads();
    for (int off = 1; off < 256; off <<= 1) {
        int t = (tid >= off) ? ssum[tid - off] : 0;
        __syncthreads();
        ssum[tid] += t;
        __syncthreads();
    }
    lofs[tid] = ssum[tid] - hist[tid];

    if (tid < nn) row_off[n0 + tid] = base + lofs[tid];
    if (b == 0 && tid == 0) row_off[N] = E;
    __syncthreads();

    hist[tid] = 0;
    __syncthreads();

    for (int i = tid; i < cnt; i += 256) {
        const unsigned int k = inb[i];
        const int node = k >> 17;
        const int l = lofs[node] + atomicAdd(&hist[node], 1);
        outv[l] = (int)(k & 0x1FFFF);
    }
    __syncthreads();

    for (int i = tid; i < cnt; i += 256)
        col[base + i] = outv[i];
}

// ---------------------------------------------------------------- aggregation
// One wave/node; gather loop as r10 (uint4, 32-bit offsets, unpredicated main
// + predicated tail). Epilogues:
//   MODE 0 (F=64): + gemm1 fused: 48 outs = {g2[32], pre3 RMW[16]}, Wk=Wt1.
//   MODE 1 (F=32): pre2 add; + gemm2 fused: 16 outs -> g3, Wk=Wt2.
//   MODE 2 (F=16): pre3 add; output head -> sigmoid.

template<int F, int MODE>
__global__ __launch_bounds__(256) void agg_kernel(
    const ushort* __restrict__ g, const float* __restrict__ dinv,
    const int* __restrict__ row_off, const int* __restrict__ col,
    const float* __restrict__ bias, const float* __restrict__ pre,
    const ushort* __restrict__ Wk, const float* __restrict__ bs13,
    const float* __restrict__ Wout, const float* __restrict__ bout,
    void* __restrict__ out, float* __restrict__ pre3, int N)
{
    constexpr int FG  = F / 8;            // lanes per edge
    constexpr int EPW = 64 / FG;          // edges in flight per wave
    constexpr int U   = 32 / EPW;         // bursts so U*EPW = 32 slots
    constexpr int LSH = (F == 64) ? 7 : (F == 32 ? 6 : 5);  // log2(row bytes)

    const int lane = threadIdx.x & 63;
    const int wv   = threadIdx.x >> 6;
    const int i    = blockIdx.x * 4 + wv;
    if (i >= N) return;

    const int fg  = lane & (FG - 1);
    const int eo  = lane / FG;
    const unsigned fbb = (unsigned)fg * 16;   // byte offset of lane's 8 feats

    const char* gb = (const char*)g;

    f2_t acc0 = {0.f, 0.f}, acc1 = {0.f, 0.f};
    f2_t acc2 = {0.f, 0.f}, acc3 = {0.f, 0.f};

    const int s = row_off[i], e = row_off[i + 1];
    const int nfull = (e - s) >> 5;
    int p = s;
    const int* cp = col + s + eo;

    for (int it = 0; it < nfull; ++it, p += 32, cp += 32) {
        unsigned voff[U];
#pragma unroll
        for (int u = 0; u < U; ++u)
            voff[u] = ((unsigned)cp[u * EPW] << LSH) + fbb;
        uint4 w[U];
#pragma unroll
        for (int u = 0; u < U; ++u)
            w[u] = *reinterpret_cast<const uint4*>(gb + voff[u]);
#pragma unroll
        for (int u = 0; u < U; ++u) {
            acc0 += (f2_t){uaf(w[u].x << 16), uaf(w[u].x & 0xffff0000u)};
            acc1 += (f2_t){uaf(w[u].y << 16), uaf(w[u].y & 0xffff0000u)};
            acc2 += (f2_t){uaf(w[u].z << 16), uaf(w[u].z & 0xffff0000u)};
            acc3 += (f2_t){uaf(w[u].w << 16), uaf(w[u].w & 0xffff0000u)};
        }
    }
    if (p < e) {
        float m[U];
        unsigned voff[U];
#pragma unroll
        for (int u = 0; u < U; ++u) {
            const int q = p + eo + u * EPW;
            m[u]    = (q < e) ? 1.0f : 0.0f;
            voff[u] = ((unsigned)col[min(q, e - 1)] << LSH) + fbb;
        }
        uint4 w[U];
#pragma unroll
        for (int u = 0; u < U; ++u)
            w[u] = *reinterpret_cast<const uint4*>(gb + voff[u]);
#pragma unroll
        for (int u = 0; u < U; ++u) {
            const f2_t mm = {m[u], m[u]};
            acc0 += mm * (f2_t){uaf(w[u].x << 16), uaf(w[u].x & 0xffff0000u)};
            acc1 += mm * (f2_t){uaf(w[u].y << 16), uaf(w[u].y & 0xffff0000u)};
            acc2 += mm * (f2_t){uaf(w[u].z << 16), uaf(w[u].z & 0xffff0000u)};
            acc3 += mm * (f2_t){uaf(w[u].w << 16), uaf(w[u].w & 0xffff0000u)};
        }
    }

#pragma unroll
    for (int ro = FG; ro < 64; ro <<= 1) {
        acc0.x += __shfl_xor(acc0.x, ro); acc0.y += __shfl_xor(acc0.y, ro);
        acc1.x += __shfl_xor(acc1.x, ro); acc1.y += __shfl_xor(acc1.y, ro);
        acc2.x += __shfl_xor(acc2.x, ro); acc2.y += __shfl_xor(acc2.y, ro);
        acc3.x += __shfl_xor(acc3.x, ro); acc3.y += __shfl_xor(acc3.y, ro);
    }

    const uint4 ws =
        *reinterpret_cast<const uint4*>(gb + (((unsigned)i) << LSH) + fbb);
    const float di = dinv[i];
    const int fb = fg * 8;
    const float4 b0 = *reinterpret_cast<const float4*>(&bias[fb]);
    const float4 b1 = *reinterpret_cast<const float4*>(&bias[fb + 4]);

    float v0 = di * (acc0.x + uaf(ws.x << 16))         + b0.x;
    float v1 = di * (acc0.y + uaf(ws.x & 0xffff0000u)) + b0.y;
    float v2 = di * (acc1.x + uaf(ws.y << 16))         + b0.z;
    float v3 = di * (acc1.y + uaf(ws.y & 0xffff0000u)) + b0.w;
    float v4 = di * (acc2.x + uaf(ws.z << 16))         + b1.x;
    float v5 = di * (acc2.y + uaf(ws.z & 0xffff0000u)) + b1.y;
    float v6 = di * (acc3.x + uaf(ws.w << 16))         + b1.z;
    float v7 = di * (acc3.y + uaf(ws.w & 0xffff0000u)) + b1.w;

    if (MODE != 0) {
        const float4 p0 = *reinterpret_cast<const float4*>(&pre[(size_t)i * F + fb]);
        const float4 p1 = *reinterpret_cast<const float4*>(&pre[(size_t)i * F + fb + 4]);
        v0 += p0.x; v1 += p0.y; v2 += p0.z; v3 += p0.w;
        v4 += p1.x; v5 += p1.y; v6 += p1.z; v7 += p1.w;
    }
    v0 = fmaxf(v0, 0.f); v1 = fmaxf(v1, 0.f);
    v2 = fmaxf(v2, 0.f); v3 = fmaxf(v3, 0.f);
    v4 = fmaxf(v4, 0.f); v5 = fmaxf(v5, 0.f);
    v6 = fmaxf(v6, 0.f); v7 = fmaxf(v7, 0.f);

    if (MODE == 0) {
        // fused gemm1: 48 outputs, lane handles f = eo*6 + t over its 8 k's.
        float pacc[6];
#pragma unroll
        for (int t = 0; t < 6; ++t) {
            const int f = eo * 6 + t;
            const uint4 wr = *reinterpret_cast<const uint4*>(&Wk[f * 64 + fb]);
            float sacc;
            sacc  = v0 * uaf(wr.x << 16);
            sacc += v1 * uaf(wr.x & 0xffff0000u);
            sacc += v2 * uaf(wr.y << 16);
            sacc += v3 * uaf(wr.y & 0xffff0000u);
            sacc += v4 * uaf(wr.z << 16);
            sacc += v5 * uaf(wr.z & 0xffff0000u);
            sacc += v6 * uaf(wr.w << 16);
            sacc += v7 * uaf(wr.w & 0xffff0000u);
            pacc[t] = sacc;
        }
#pragma unroll
        for (int t = 0; t < 6; ++t) {
            pacc[t] += __shfl_xor(pacc[t], 1);
            pacc[t] += __shfl_xor(pacc[t], 2);
            pacc[t] += __shfl_xor(pacc[t], 4);
        }
        if ((lane & 7) == 0) {
#pragma unroll
            for (int t = 0; t < 6; ++t) {
                const int f = eo * 6 + t;
                if (f < 32) {
                    ((ushort*)out)[(size_t)i * 32 + f] = f2bf(di * pacc[t]);
                } else {
                    pre3[(size_t)i * 16 + (f - 32)] += pacc[t] + bs13[f - 32];
                }
            }
        }
    } else if (MODE == 1) {
        // fused gemm2: 16 outputs, lane eo handles output eo over its 8 k's.
        const uint4 wr = *reinterpret_cast<const uint4*>(&Wk[eo * 32 + fb]);
        float sacc;
        sacc  = v0 * uaf(wr.x << 16);
        sacc += v1 * uaf(wr.x & 0xffff0000u);
        sacc += v2 * uaf(wr.y << 16);
        sacc += v3 * uaf(wr.y & 0xffff0000u);
        sacc += v4 * uaf(wr.z << 16);
        sacc += v5 * uaf(wr.z & 0xffff0000u);
        sacc += v6 * uaf(wr.w << 16);
        sacc += v7 * uaf(wr.w & 0xffff0000u);
        sacc += __shfl_xor(sacc, 1);
        sacc += __shfl_xor(sacc, 2);
        if ((lane & 3) == 0)
            ((ushort*)out)[(size_t)i * 16 + eo] = f2bf(di * sacc);
    } else {
        const float4 w0 = *reinterpret_cast<const float4*>(&Wout[fb]);
        const float4 w1 = *reinterpret_cast<const float4*>(&Wout[fb + 4]);
        float t = v0 * w0.x + v1 * w0.y + v2 * w0.z + v3 * w0.w +
                  v4 * w1.x + v5 * w1.y + v6 * w1.z + v7 * w1.w;
        t += __shfl_xor(t, 1);               // FG == 2
        if (lane == 0)
            ((float*)out)[i] = 1.0f / (1.0f + expf(-(t + bout[0])));
    }
}

// ---------------------------------------------------------------- launch

extern "C" void kernel_launch(void* const* d_in, const int* in_sizes, int n_in,
                              void* d_out, int out_size, void* d_ws, size_t ws_size,
                              hipStream_t stream)
{
    const float* x    = (const float*)d_in[0];
    const int*   edge = (const int*)d_in[1];
    const float* W1   = (const float*)d_in[2];
    const float* b1   = (const float*)d_in[3];
    const float* W2   = (const float*)d_in[4];
    const float* b2   = (const float*)d_in[5];
    const float* W3   = (const float*)d_in[6];
    const float* b3   = (const float*)d_in[7];
    const float* Ws02 = (const float*)d_in[8];
    const float* bs02 = (const float*)d_in[9];
    const float* Ws03 = (const float*)d_in[10];
    const float* bs03 = (const float*)d_in[11];
    const float* Ws13 = (const float*)d_in[12];
    const float* bs13 = (const float*)d_in[13];
    const float* Wout = (const float*)d_in[14];
    const float* bout = (const float*)d_in[15];

    const int N = in_sizes[0] / 256;
    const int E = in_sizes[1] / 2;
    const int* srcv = edge;
    const int* dstv = edge + E;
    const int nbuckets = (N + 255) >> 8;

    char* ws = (char*)d_ws;
    size_t off = 0;
    auto alloc = [&](size_t bytes) -> void* {
        void* p = ws + off;
        off += (bytes + 255) & ~(size_t)255;
        return p;
    };
    unsigned int* keys = (unsigned int*)alloc((size_t)E * 4);
    int*   col      = (int*)  alloc((size_t)E * 4);
    int*   bcount   = (int*)  alloc((size_t)NBUCK_MAX * 4);
    int*   deg      = (int*)  alloc((size_t)N * 4);      // contiguous w/ bcount
    int*   bbase    = (int*)  alloc((size_t)NBUCK_MAX * 4);
    int*   bcursor  = (int*)  alloc((size_t)NBUCK_MAX * 4);
    int*   row_off  = (int*)  alloc((size_t)(N + 1) * 4);
    float* dinv     = (float*)alloc((size_t)N * 4);
    ushort* Wt0     = (ushort*)alloc((size_t)128 * 256 * 2);
    ushort* Wt1     = (ushort*)alloc((size_t)48 * 64 * 2);
    ushort* Wt2     = (ushort*)alloc((size_t)16 * 32 * 2);
    ushort* g1      = (ushort*)alloc((size_t)N * 64 * 2);
    ushort* g2      = (ushort*)alloc((size_t)N * 32 * 2);
    ushort* g3      = (ushort*)alloc((size_t)N * 16 * 2);
    float* pre2     = (float*)alloc((size_t)N * 32 * 4);
    float* pre3     = (float*)alloc((size_t)N * 16 * 4);

    // zero bcount + deg in one memset (adjacent allocations)
    hipMemsetAsync(bcount, 0, (size_t)NBUCK_MAX * 4 + (size_t)N * 4, stream);

    // FKA: weight prep ∥ bucket hist + node degree
    fka_kernel<<<PREP_BLOCKS + HIST_BLOCKS, 256, 0, stream>>>(
        W1, Ws02, Ws03, W2, Ws13, W3, Wt0, Wt1, Wt2,
        dstv, E, bcount, deg, nbuckets);

    // FKS: bucket scan ∥ dinv
    fks_kernel<<<1 + (N + 511) / 512, 512, 0, stream>>>(
        bcount, bbase, bcursor, deg, dinv, nbuckets, N);

    // FKB: partition ∥ gemm0
    const int PB = (E + P1_CHUNK - 1) / P1_CHUNK;
    fkb_kernel<<<PB + (N + 63) / 64, 256, 0, stream>>>(
        srcv, dstv, E, bcursor, keys, nbuckets, PB,
        x, Wt0, bs02, bs03, dinv, g1, pre2, pre3, N);

    // CSR build
    csr_build_kernel<<<nbuckets, 256, 0, stream>>>(
        keys, bbase, bcount, row_off, col, N, E);

    const int ab = (N + 3) / 4;

    // layer-1 aggregate + fused gemm1 (-> g2, pre3 RMW)
    agg_kernel<64, 0><<<ab, 256, 0, stream>>>(
        g1, dinv, row_off, col, b1, nullptr, Wt1, bs13,
        nullptr, nullptr, g2, pre3, N);
    // layer-2 aggregate (+pre2) + fused gemm2 (-> g3)
    agg_kernel<32, 1><<<ab, 256, 0, stream>>>(
        g2, dinv, row_off, col, b2, pre2, Wt2, nullptr,
        nullptr, nullptr, g3, nullptr, N);
    // layer-3 aggregate (+pre3) + output head
    agg_kernel<16, 2><<<ab, 256, 0, stream>>>(
        g3, dinv, row_off, col, b3, pre3, nullptr, nullptr,
        Wout, bout, d_out, nullptr, N);
}

// Round 4
// 454.084 us; speedup vs baseline: 1.2310x; 1.2310x over previous
//
#include <hip/hip_runtime.h>
#include <hip/hip_bf16.h>
#include <math.h>

// DenseGCN3Layer on MI355X — round 12.
// Changes vs r11 (which regressed: 3.2M global deg atomics in FKA = 143µs):
//  * deg atomics REMOVED. dinv computed in csr_build again (per-bucket LDS
//    hist, as r10).
//  * dinv->gemm0 dependency broken the cheap way instead: gemm0 writes
//    g1 = h (UNSCALED); layer-1 agg applies dinv[col] at gather time
//    (4B broadcast load from L2-resident 400KB array, add becomes fma),
//    self term = di^2 * h[i]. Layers 2/3 keep pre-scaled scheme.
//  * Keeps from r11: FKA{prep ∥ hist}, FKB{partition ∥ gemm0}, gemm1 fused
//    into agg<64> epilogue, gemm2 fused into agg<32> epilogue.
//  * 8 dispatches total.

#define NBUCK_MAX 512
#define P1_CHUNK 4096
#define EPT 16
#define BCAP 9216
#define PREP_BLOCKS 142
#define HIST_BLOCKS 1024

typedef __attribute__((ext_vector_type(8))) short bfrag;   // 8 bf16 (4 VGPR)
typedef __attribute__((ext_vector_type(4))) float f4_t;    // acc
typedef __attribute__((ext_vector_type(2))) float f2_t;    // packed pair

__device__ inline float uaf(unsigned u) { return __uint_as_float(u); }
__device__ inline ushort f2bf(float f) {
    __hip_bfloat16 b = __float2bfloat16(f);
    return *reinterpret_cast<ushort*>(&b);
}
__device__ inline bfrag cvt8(const float4 a, const float4 b) {
    union { ushort u[8]; bfrag f; } r;
    r.u[0] = f2bf(a.x); r.u[1] = f2bf(a.y); r.u[2] = f2bf(a.z); r.u[3] = f2bf(a.w);
    r.u[4] = f2bf(b.x); r.u[5] = f2bf(b.y); r.u[6] = f2bf(b.z); r.u[7] = f2bf(b.w);
    return r.f;
}
__device__ inline bfrag ld_bfrag(const ushort* p) {
    const uint4 raw = *reinterpret_cast<const uint4*>(p);
    return *reinterpret_cast<const bfrag*>(&raw);
}

// ------------------------------------------------ FKA: prep ∥ hist

__global__ __launch_bounds__(256) void fka_kernel(
    const float* __restrict__ W1, const float* __restrict__ Ws02,
    const float* __restrict__ Ws03, const float* __restrict__ W2,
    const float* __restrict__ Ws13, const float* __restrict__ W3,
    ushort* __restrict__ Wt0, ushort* __restrict__ Wt1, ushort* __restrict__ Wt2,
    const int* __restrict__ dst, int E, int* __restrict__ bucket_count,
    int nbuckets)
{
    if (blockIdx.x < PREP_BLOCKS) {
        const int idx = blockIdx.x * 256 + threadIdx.x;
        if (idx < 32768) {
            int f = idx >> 8, k = idx & 255;
            float v = 0.f;
            if (f < 64)       v = W1[k * 64 + f];
            else if (f < 96)  v = Ws02[k * 32 + (f - 64)];
            else if (f < 112) v = Ws03[k * 16 + (f - 96)];
            Wt0[idx] = f2bf(v);
        } else if (idx < 32768 + 3072) {
            int t = idx - 32768;
            int f = t >> 6, k = t & 63;
            float v = (f < 32) ? W2[k * 32 + f] : Ws13[k * 16 + (f - 32)];
            Wt1[t] = f2bf(v);
        } else if (idx < 32768 + 3072 + 512) {
            int t = idx - 32768 - 3072;
            int f = t >> 5, k = t & 31;
            Wt2[t] = f2bf(W3[k * 16 + f]);
        }
        return;
    }
    // hist role (LDS atomics only)
    __shared__ int lhist[NBUCK_MAX];
    const int bid = blockIdx.x - PREP_BLOCKS;
    for (int i = threadIdx.x; i < nbuckets; i += 256) lhist[i] = 0;
    __syncthreads();
    const int stride = HIST_BLOCKS * 256;
    for (int e = bid * 256 + threadIdx.x; e < E; e += stride)
        atomicAdd(&lhist[dst[e] >> 8], 1);
    __syncthreads();
    for (int i = threadIdx.x; i < nbuckets; i += 256) {
        int c = lhist[i];
        if (c) atomicAdd(&bucket_count[i], c);
    }
}

// ------------------------------------------------ scan

__global__ __launch_bounds__(512) void bucket_scan_kernel(
    const int* __restrict__ bucket_count, int* __restrict__ bucket_base,
    int* __restrict__ bucket_cursor, int nbuckets)
{
    __shared__ int tmp[512];
    const int tid = threadIdx.x;
    int v = (tid < nbuckets) ? bucket_count[tid] : 0;
    tmp[tid] = v;
    __syncthreads();
    for (int off = 1; off < 512; off <<= 1) {
        int t = (tid >= off) ? tmp[tid - off] : 0;
        __syncthreads();
        tmp[tid] += t;
        __syncthreads();
    }
    if (tid < nbuckets) {
        int base = tmp[tid] - v;
        bucket_base[tid]   = base;
        bucket_cursor[tid] = base;
    }
}

// ------------------------------------------------ FKB: partition ∥ gemm0

union FKBsh {
    float xs[2][4096];                       // gemm0: 2 x 16 KB
    struct {
        int hist[NBUCK_MAX];
        int lofs[NBUCK_MAX];
        int gbase[NBUCK_MAX];
        int lcur[NBUCK_MAX];
        int ssum[256];
        unsigned int stage[P1_CHUNK];
        int gidx[P1_CHUNK];
    } p;                                     // partition: ~41 KB
};

__global__ __launch_bounds__(256, 3) void fkb_kernel(
    // partition role
    const int* __restrict__ src, const int* __restrict__ dst, int E,
    int* __restrict__ bucket_cursor, unsigned int* __restrict__ keys,
    int nbuckets, int part_blocks,
    // gemm0 role (NO dinv — writes unscaled h)
    const float* __restrict__ X, const ushort* __restrict__ Wt0,
    const float* __restrict__ bs02, const float* __restrict__ bs03,
    ushort* __restrict__ g1, float* __restrict__ pre2,
    float* __restrict__ pre3, int N)
{
    __shared__ __align__(16) FKBsh sh;
    const int tid = threadIdx.x;

    if (blockIdx.x < part_blocks) {
        // ---------------- partition role ----------------
        const int e0 = blockIdx.x * P1_CHUNK;
        const int nE = min(P1_CHUNK, E - e0);

        for (int i = tid; i < NBUCK_MAX; i += 256) { sh.p.hist[i] = 0; sh.p.lcur[i] = 0; }
        __syncthreads();

        int myb[EPT];
        unsigned int mypk[EPT];
#pragma unroll
        for (int j = 0; j < EPT; ++j) {
            const int e = e0 + tid + j * 256;
            if (e < E) {
                const int d = dst[e];
                myb[j]  = d >> 8;
                mypk[j] = ((unsigned int)(d & 255) << 17) | (unsigned int)src[e];
                atomicAdd(&sh.p.hist[myb[j]], 1);
            } else myb[j] = -1;
        }
        __syncthreads();

        int a0 = (2 * tid     < nbuckets) ? sh.p.hist[2 * tid]     : 0;
        int a1 = (2 * tid + 1 < nbuckets) ? sh.p.hist[2 * tid + 1] : 0;
        sh.p.ssum[tid] = a0 + a1;
        __syncthreads();
        for (int off = 1; off < 256; off <<= 1) {
            int t = (tid >= off) ? sh.p.ssum[tid - off] : 0;
            __syncthreads();
            sh.p.ssum[tid] += t;
            __syncthreads();
        }
        const int ex = sh.p.ssum[tid] - (a0 + a1);
        if (2 * tid     < nbuckets) sh.p.lofs[2 * tid]     = ex;
        if (2 * tid + 1 < nbuckets) sh.p.lofs[2 * tid + 1] = ex + a0;
        __syncthreads();

        for (int i = tid; i < nbuckets; i += 256)
            sh.p.gbase[i] = atomicAdd(&bucket_cursor[i], sh.p.hist[i]);
        __syncthreads();

#pragma unroll
        for (int j = 0; j < EPT; ++j) {
            if (myb[j] >= 0) {
                const int b = myb[j];
                const int l = sh.p.lofs[b] + atomicAdd(&sh.p.lcur[b], 1);
                sh.p.stage[l] = mypk[j];
                sh.p.gidx[l]  = sh.p.gbase[b] - sh.p.lofs[b] + l;
            }
        }
        __syncthreads();

        for (int i = tid; i < nE; i += 256)
            keys[sh.p.gidx[i]] = sh.p.stage[i];
        return;
    }

    // ---------------- gemm0 role ----------------
    const int bid  = blockIdx.x - part_blocks;
    const int lane = tid & 63;
    const int wf   = tid >> 6;
    const int n0   = bid * 64;
    const int mrow = lane & 15;
    const int q    = lane >> 4;
    const int kq   = q * 8;

    bfrag bfr[2][8];
#pragma unroll
    for (int ft = 0; ft < 2; ++ft) {
        const ushort* wr = &Wt0[(size_t)(wf * 32 + ft * 16 + mrow) * 256 + kq];
#pragma unroll
        for (int p = 0; p < 8; ++p)
            bfr[ft][p] = ld_bfrag(&wr[p * 32]);
    }

    int srow[4], schunk[4];
#pragma unroll
    for (int j = 0; j < 4; ++j) {
        const int R = wf * 16 + j * 4 + q;
        srow[j]   = min(n0 + R, N - 1);
        schunk[j] = mrow ^ (R & 7);
    }

    auto STAGE = [&](int buf, int kc) {
#pragma unroll
        for (int j = 0; j < 4; ++j) {
            const float* gsrc =
                X + (size_t)srow[j] * 256 + kc * 64 + schunk[j] * 4;
            __builtin_amdgcn_global_load_lds(
                (const __attribute__((address_space(1))) unsigned int*)gsrc,
                (__attribute__((address_space(3))) unsigned int*)
                    &sh.xs[buf][(wf * 16 + j * 4) * 64],
                16, 0, 0);
        }
    };

    f4_t acc[4][2];
#pragma unroll
    for (int a = 0; a < 4; ++a)
#pragma unroll
        for (int b = 0; b < 2; ++b) acc[a][b] = {0.f, 0.f, 0.f, 0.f};

    STAGE(0, 0);
    __syncthreads();

    int cur = 0;
    for (int kc = 0; kc < 4; ++kc) {
        if (kc < 3) STAGE(cur ^ 1, kc + 1);
        const float4* Xs4 = reinterpret_cast<const float4*>(&sh.xs[cur][0]);
#pragma unroll
        for (int pl = 0; pl < 2; ++pl) {
            bfrag af[4];
#pragma unroll
            for (int mt = 0; mt < 4; ++mt) {
                const int r  = mt * 16 + mrow;
                const int c0 = pl * 8 + q * 2;
                const float4 u0 = Xs4[r * 16 + (c0 ^ (r & 7))];
                const float4 u1 = Xs4[r * 16 + ((c0 + 1) ^ (r & 7))];
                af[mt] = cvt8(u0, u1);
            }
            const int pg = kc * 2 + pl;
#pragma unroll
            for (int mt = 0; mt < 4; ++mt)
#pragma unroll
                for (int ft = 0; ft < 2; ++ft)
                    acc[mt][ft] = __builtin_amdgcn_mfma_f32_16x16x32_bf16(
                        af[mt], bfr[ft][pg], acc[mt][ft], 0, 0, 0);
        }
        __syncthreads();
        cur ^= 1;
    }

    // staged epilogue (reuses LDS); g1 = UNSCALED h
    char* sm = (char*)&sh;
    ushort* g1s = (ushort*)sm;                   // [64][64]  8 KB
    float*  p2s = (float*)(sm + 8192);           // [64][32]  8 KB
    float*  p3s = (float*)(sm + 16384);          // [64][16]  4 KB

    if (wf < 2) {
#pragma unroll
        for (int mt = 0; mt < 4; ++mt) {
#pragma unroll
            for (int r = 0; r < 4; ++r) {
                const int nl = mt * 16 + q * 4 + r;
#pragma unroll
                for (int ft = 0; ft < 2; ++ft)
                    g1s[nl * 64 + wf * 32 + ft * 16 + mrow] =
                        f2bf(acc[mt][ft][r]);
            }
        }
    } else if (wf == 2) {
#pragma unroll
        for (int mt = 0; mt < 4; ++mt)
#pragma unroll
            for (int ft = 0; ft < 2; ++ft)
#pragma unroll
                for (int r = 0; r < 4; ++r)
                    p2s[(mt * 16 + q * 4 + r) * 32 + ft * 16 + mrow] =
                        acc[mt][ft][r] + bs02[ft * 16 + mrow];
    } else {
#pragma unroll
        for (int mt = 0; mt < 4; ++mt)
#pragma unroll
            for (int r = 0; r < 4; ++r)
                p3s[(mt * 16 + q * 4 + r) * 16 + mrow] =
                    acc[mt][0][r] + bs03[mrow];
    }
    __syncthreads();

    const uint4* g1v = (const uint4*)g1s;
    const uint4* p2v = (const uint4*)p2s;
    const uint4* p3v = (const uint4*)p3s;
#pragma unroll
    for (int t = 0; t < 2; ++t) {
        const int i   = t * 256 + tid;
        const int row = i >> 3;
        if (n0 + row < N)
            *(uint4*)(g1 + (size_t)(n0 + row) * 64 + (i & 7) * 8) = g1v[i];
    }
#pragma unroll
    for (int t = 0; t < 2; ++t) {
        const int i   = t * 256 + tid;
        const int row = i >> 3;
        if (n0 + row < N)
            *(uint4*)(pre2 + (size_t)(n0 + row) * 32 + (i & 7) * 4) = p2v[i];
    }
    {
        const int i   = tid;
        const int row = i >> 2;
        if (n0 + row < N)
            *(uint4*)(pre3 + (size_t)(n0 + row) * 16 + (i & 3) * 4) = p3v[i];
    }
}

// ------------------------------------------------ csr build (+ dinv, as r10)

__global__ __launch_bounds__(256) void csr_build_kernel(
    const unsigned int* __restrict__ keys, const int* __restrict__ bucket_base,
    const int* __restrict__ bucket_count,
    int* __restrict__ row_off, float* __restrict__ dinv, int* __restrict__ col,
    int N, int E)
{
    __shared__ unsigned int inb[BCAP];
    __shared__ int outv[BCAP];
    __shared__ int hist[256];
    __shared__ int lofs[256];
    __shared__ int ssum[256];

    const int tid  = threadIdx.x;
    const int b    = blockIdx.x;
    const int base = bucket_base[b];
    const int cnt  = min(bucket_count[b], BCAP);
    const int n0   = b << 8;
    const int nn   = min(256, N - n0);

    for (int i = tid; i < cnt; i += 256) inb[i] = keys[base + i];
    hist[tid] = 0;
    __syncthreads();

    for (int i = tid; i < cnt; i += 256)
        atomicAdd(&hist[inb[i] >> 17], 1);
    __syncthreads();

    ssum[tid] = hist[tid];
    __syncthreads();
    for (int off = 1; off < 256; off <<= 1) {
        int t = (tid >= off) ? ssum[tid - off] : 0;
        __syncthreads();
        ssum[tid] += t;
        __syncthreads();
    }
    lofs[tid] = ssum[tid] - hist[tid];

    if (tid < nn) {
        row_off[n0 + tid] = base + lofs[tid];
        dinv[n0 + tid]    = rsqrtf((float)hist[tid] + 1.0f);
    }
    if (b == 0 && tid == 0) row_off[N] = E;
    __syncthreads();

    hist[tid] = 0;
    __syncthreads();

    for (int i = tid; i < cnt; i += 256) {
        const unsigned int k = inb[i];
        const int node = k >> 17;
        const int l = lofs[node] + atomicAdd(&hist[node], 1);
        outv[l] = (int)(k & 0x1FFFF);
    }
    __syncthreads();

    for (int i = tid; i < cnt; i += 256)
        col[base + i] = outv[i];
}

// ---------------------------------------------------------------- aggregation
// One wave/node; uint4 gathers, 32-bit offsets, unpredicated main loop +
// predicated tail. MODE 0 gathers UNSCALED g1 and applies dinv[col] per edge
// (fma with broadcast 4B load); self term = di^2 * h[i]. MODE 1/2 inputs are
// pre-scaled. Epilogues:
//   MODE 0 (F=64): + gemm1 fused: {g2[32] (di-scaled), pre3 RMW[16]}, Wk=Wt1.
//   MODE 1 (F=32): pre2 add; + gemm2 fused: 16 outs -> g3 (di-scaled), Wk=Wt2.
//   MODE 2 (F=16): pre3 add; output head -> sigmoid.

template<int F, int MODE>
__global__ __launch_bounds__(256) void agg_kernel(
    const ushort* __restrict__ g, const float* __restrict__ dinv,
    const int* __restrict__ row_off, const int* __restrict__ col,
    const float* __restrict__ bias, const float* __restrict__ pre,
    const ushort* __restrict__ Wk, const float* __restrict__ bs13,
    const float* __restrict__ Wout, const float* __restrict__ bout,
    void* __restrict__ out, float* __restrict__ pre3, int N)
{
    constexpr int FG  = F / 8;            // lanes per edge
    constexpr int EPW = 64 / FG;          // edges in flight per wave
    constexpr int U   = 32 / EPW;         // bursts so U*EPW = 32 slots
    constexpr int LSH = (F == 64) ? 7 : (F == 32 ? 6 : 5);  // log2(row bytes)
    constexpr bool GDV = (MODE == 0);     // gather-time dinv[col]

    const int lane = threadIdx.x & 63;
    const int wv   = threadIdx.x >> 6;
    const int i    = blockIdx.x * 4 + wv;
    if (i >= N) return;

    const int fg  = lane & (FG - 1);
    const int eo  = lane / FG;
    const unsigned fbb = (unsigned)fg * 16;   // byte offset of lane's 8 feats

    const char* gb = (const char*)g;

    f2_t acc0 = {0.f, 0.f}, acc1 = {0.f, 0.f};
    f2_t acc2 = {0.f, 0.f}, acc3 = {0.f, 0.f};

    const int s = row_off[i], e = row_off[i + 1];
    const int nfull = (e - s) >> 5;
    int p = s;
    const int* cp = col + s + eo;

    for (int it = 0; it < nfull; ++it, p += 32, cp += 32) {
        unsigned voff[U];
        float dv[U];
#pragma unroll
        for (int u = 0; u < U; ++u) {
            const int js = cp[u * EPW];
            voff[u] = ((unsigned)js << LSH) + fbb;
            if (GDV) dv[u] = dinv[js];
        }
        uint4 w[U];
#pragma unroll
        for (int u = 0; u < U; ++u)
            w[u] = *reinterpret_cast<const uint4*>(gb + voff[u]);
#pragma unroll
        for (int u = 0; u < U; ++u) {
            if (GDV) {
                const f2_t mm = {dv[u], dv[u]};
                acc0 += mm * (f2_t){uaf(w[u].x << 16), uaf(w[u].x & 0xffff0000u)};
                acc1 += mm * (f2_t){uaf(w[u].y << 16), uaf(w[u].y & 0xffff0000u)};
                acc2 += mm * (f2_t){uaf(w[u].z << 16), uaf(w[u].z & 0xffff0000u)};
                acc3 += mm * (f2_t){uaf(w[u].w << 16), uaf(w[u].w & 0xffff0000u)};
            } else {
                acc0 += (f2_t){uaf(w[u].x << 16), uaf(w[u].x & 0xffff0000u)};
                acc1 += (f2_t){uaf(w[u].y << 16), uaf(w[u].y & 0xffff0000u)};
                acc2 += (f2_t){uaf(w[u].z << 16), uaf(w[u].z & 0xffff0000u)};
                acc3 += (f2_t){uaf(w[u].w << 16), uaf(w[u].w & 0xffff0000u)};
            }
        }
    }
    if (p < e) {
        float m[U];
        unsigned voff[U];
#pragma unroll
        for (int u = 0; u < U; ++u) {
            const int q = p + eo + u * EPW;
            const int js = col[min(q, e - 1)];
            const float live = (q < e) ? 1.0f : 0.0f;
            m[u]    = GDV ? live * dinv[js] : live;
            voff[u] = ((unsigned)js << LSH) + fbb;
        }
        uint4 w[U];
#pragma unroll
        for (int u = 0; u < U; ++u)
            w[u] = *reinterpret_cast<const uint4*>(gb + voff[u]);
#pragma unroll
        for (int u = 0; u < U; ++u) {
            const f2_t mm = {m[u], m[u]};
            acc0 += mm * (f2_t){uaf(w[u].x << 16), uaf(w[u].x & 0xffff0000u)};
            acc1 += mm * (f2_t){uaf(w[u].y << 16), uaf(w[u].y & 0xffff0000u)};
            acc2 += mm * (f2_t){uaf(w[u].z << 16), uaf(w[u].z & 0xffff0000u)};
            acc3 += mm * (f2_t){uaf(w[u].w << 16), uaf(w[u].w & 0xffff0000u)};
        }
    }

#pragma unroll
    for (int ro = FG; ro < 64; ro <<= 1) {
        acc0.x += __shfl_xor(acc0.x, ro); acc0.y += __shfl_xor(acc0.y, ro);
        acc1.x += __shfl_xor(acc1.x, ro); acc1.y += __shfl_xor(acc1.y, ro);
        acc2.x += __shfl_xor(acc2.x, ro); acc2.y += __shfl_xor(acc2.y, ro);
        acc3.x += __shfl_xor(acc3.x, ro); acc3.y += __shfl_xor(acc3.y, ro);
    }

    const uint4 ws =
        *reinterpret_cast<const uint4*>(gb + (((unsigned)i) << LSH) + fbb);
    const float di = dinv[i];
    const float sw = GDV ? di * di : di;   // self-term weight
    const int fb = fg * 8;
    const float4 b0 = *reinterpret_cast<const float4*>(&bias[fb]);
    const float4 b1 = *reinterpret_cast<const float4*>(&bias[fb + 4]);

    float v0 = di * acc0.x + sw * uaf(ws.x << 16)         + b0.x;
    float v1 = di * acc0.y + sw * uaf(ws.x & 0xffff0000u) + b0.y;
    float v2 = di * acc1.x + sw * uaf(ws.y << 16)         + b0.z;
    float v3 = di * acc1.y + sw * uaf(ws.y & 0xffff0000u) + b0.w;
    float v4 = di * acc2.x + sw * uaf(ws.z << 16)         + b1.x;
    float v5 = di * acc2.y + sw * uaf(ws.z & 0xffff0000u) + b1.y;
    float v6 = di * acc3.x + sw * uaf(ws.w << 16)         + b1.z;
    float v7 = di * acc3.y + sw * uaf(ws.w & 0xffff0000u) + b1.w;

    if (MODE != 0) {
        const float4 p0 = *reinterpret_cast<const float4*>(&pre[(size_t)i * F + fb]);
        const float4 p1 = *reinterpret_cast<const float4*>(&pre[(size_t)i * F + fb + 4]);
        v0 += p0.x; v1 += p0.y; v2 += p0.z; v3 += p0.w;
        v4 += p1.x; v5 += p1.y; v6 += p1.z; v7 += p1.w;
    }
    v0 = fmaxf(v0, 0.f); v1 = fmaxf(v1, 0.f);
    v2 = fmaxf(v2, 0.f); v3 = fmaxf(v3, 0.f);
    v4 = fmaxf(v4, 0.f); v5 = fmaxf(v5, 0.f);
    v6 = fmaxf(v6, 0.f); v7 = fmaxf(v7, 0.f);

    if (MODE == 0) {
        // fused gemm1: 48 outputs, lane handles f = eo*6 + t over its 8 k's.
        float pacc[6];
#pragma unroll
        for (int t = 0; t < 6; ++t) {
            const int f = eo * 6 + t;
            const uint4 wr = *reinterpret_cast<const uint4*>(&Wk[f * 64 + fb]);
            float sacc;
            sacc  = v0 * uaf(wr.x << 16);
            sacc += v1 * uaf(wr.x & 0xffff0000u);
            sacc += v2 * uaf(wr.y << 16);
            sacc += v3 * uaf(wr.y & 0xffff0000u);
            sacc += v4 * uaf(wr.z << 16);
            sacc += v5 * uaf(wr.z & 0xffff0000u);
            sacc += v6 * uaf(wr.w << 16);
            sacc += v7 * uaf(wr.w & 0xffff0000u);
            pacc[t] = sacc;
        }
#pragma unroll
        for (int t = 0; t < 6; ++t) {
            pacc[t] += __shfl_xor(pacc[t], 1);
            pacc[t] += __shfl_xor(pacc[t], 2);
            pacc[t] += __shfl_xor(pacc[t], 4);
        }
        if ((lane & 7) == 0) {
#pragma unroll
            for (int t = 0; t < 6; ++t) {
                const int f = eo * 6 + t;
                if (f < 32) {
                    ((ushort*)out)[(size_t)i * 32 + f] = f2bf(di * pacc[t]);
                } else {
                    pre3[(size_t)i * 16 + (f - 32)] += pacc[t] + bs13[f - 32];
                }
            }
        }
    } else if (MODE == 1) {
        // fused gemm2: 16 outputs, lane eo handles output eo over its 8 k's.
        const uint4 wr = *reinterpret_cast<const uint4*>(&Wk[eo * 32 + fb]);
        float sacc;
        sacc  = v0 * uaf(wr.x << 16);
        sacc += v1 * uaf(wr.x & 0xffff0000u);
        sacc += v2 * uaf(wr.y << 16);
        sacc += v3 * uaf(wr.y & 0xffff0000u);
        sacc += v4 * uaf(wr.z << 16);
        sacc += v5 * uaf(wr.z & 0xffff0000u);
        sacc += v6 * uaf(wr.w << 16);
        sacc += v7 * uaf(wr.w & 0xffff0000u);
        sacc += __shfl_xor(sacc, 1);
        sacc += __shfl_xor(sacc, 2);
        if ((lane & 3) == 0)
            ((ushort*)out)[(size_t)i * 16 + eo] = f2bf(di * sacc);
    } else {
        const float4 w0 = *reinterpret_cast<const float4*>(&Wout[fb]);
        const float4 w1 = *reinterpret_cast<const float4*>(&Wout[fb + 4]);
        float t = v0 * w0.x + v1 * w0.y + v2 * w0.z + v3 * w0.w +
                  v4 * w1.x + v5 * w1.y + v6 * w1.z + v7 * w1.w;
        t += __shfl_xor(t, 1);               // FG == 2
        if (lane == 0)
            ((float*)out)[i] = 1.0f / (1.0f + expf(-(t + bout[0])));
    }
}

// ---------------------------------------------------------------- launch

extern "C" void kernel_launch(void* const* d_in, const int* in_sizes, int n_in,
                              void* d_out, int out_size, void* d_ws, size_t ws_size,
                              hipStream_t stream)
{
    const float* x    = (const float*)d_in[0];
    const int*   edge = (const int*)d_in[1];
    const float* W1   = (const float*)d_in[2];
    const float* b1   = (const float*)d_in[3];
    const float* W2   = (const float*)d_in[4];
    const float* b2   = (const float*)d_in[5];
    const float* W3   = (const float*)d_in[6];
    const float* b3   = (const float*)d_in[7];
    const float* Ws02 = (const float*)d_in[8];
    const float* bs02 = (const float*)d_in[9];
    const float* Ws03 = (const float*)d_in[10];
    const float* bs03 = (const float*)d_in[11];
    const float* Ws13 = (const float*)d_in[12];
    const float* bs13 = (const float*)d_in[13];
    const float* Wout = (const float*)d_in[14];
    const float* bout = (const float*)d_in[15];

    const int N = in_sizes[0] / 256;
    const int E = in_sizes[1] / 2;
    const int* srcv = edge;
    const int* dstv = edge + E;
    const int nbuckets = (N + 255) >> 8;

    char* ws = (char*)d_ws;
    size_t off = 0;
    auto alloc = [&](size_t bytes) -> void* {
        void* p = ws + off;
        off += (bytes + 255) & ~(size_t)255;
        return p;
    };
    unsigned int* keys = (unsigned int*)alloc((size_t)E * 4);
    int*   col      = (int*)  alloc((size_t)E * 4);
    int*   bcount   = (int*)  alloc((size_t)NBUCK_MAX * 4);
    int*   bbase    = (int*)  alloc((size_t)NBUCK_MAX * 4);
    int*   bcursor  = (int*)  alloc((size_t)NBUCK_MAX * 4);
    int*   row_off  = (int*)  alloc((size_t)(N + 1) * 4);
    float* dinv     = (float*)alloc((size_t)N * 4);
    ushort* Wt0     = (ushort*)alloc((size_t)128 * 256 * 2);
    ushort* Wt1     = (ushort*)alloc((size_t)48 * 64 * 2);
    ushort* Wt2     = (ushort*)alloc((size_t)16 * 32 * 2);
    ushort* g1      = (ushort*)alloc((size_t)N * 64 * 2);
    ushort* g2      = (ushort*)alloc((size_t)N * 32 * 2);
    ushort* g3      = (ushort*)alloc((size_t)N * 16 * 2);
    float* pre2     = (float*)alloc((size_t)N * 32 * 4);
    float* pre3     = (float*)alloc((size_t)N * 16 * 4);

    hipMemsetAsync(bcount, 0, (size_t)NBUCK_MAX * 4, stream);

    // FKA: weight prep ∥ bucket hist
    fka_kernel<<<PREP_BLOCKS + HIST_BLOCKS, 256, 0, stream>>>(
        W1, Ws02, Ws03, W2, Ws13, W3, Wt0, Wt1, Wt2,
        dstv, E, bcount, nbuckets);

    // scan
    bucket_scan_kernel<<<1, 512, 0, stream>>>(bcount, bbase, bcursor, nbuckets);

    // FKB: partition ∥ gemm0 (gemm0 needs no dinv)
    const int PB = (E + P1_CHUNK - 1) / P1_CHUNK;
    fkb_kernel<<<PB + (N + 63) / 64, 256, 0, stream>>>(
        srcv, dstv, E, bcursor, keys, nbuckets, PB,
        x, Wt0, bs02, bs03, g1, pre2, pre3, N);

    // CSR build (+ dinv)
    csr_build_kernel<<<nbuckets, 256, 0, stream>>>(
        keys, bbase, bcount, row_off, dinv, col, N, E);

    const int ab = (N + 3) / 4;

    // layer-1 aggregate (gather-time dinv) + fused gemm1 (-> g2, pre3 RMW)
    agg_kernel<64, 0><<<ab, 256, 0, stream>>>(
        g1, dinv, row_off, col, b1, nullptr, Wt1, bs13,
        nullptr, nullptr, g2, pre3, N);
    // layer-2 aggregate (+pre2) + fused gemm2 (-> g3)
    agg_kernel<32, 1><<<ab, 256, 0, stream>>>(
        g2, dinv, row_off, col, b2, pre2, Wt2, nullptr,
        nullptr, nullptr, g3, nullptr, N);
    // layer-3 aggregate (+pre3) + output head
    agg_kernel<16, 2><<<ab, 256, 0, stream>>>(
        g3, dinv, row_off, col, b3, pre3, nullptr, nullptr,
        Wout, bout, d_out, nullptr, N);
}

// Round 5
// 426.474 us; speedup vs baseline: 1.3106x; 1.0647x over previous
//
#include <hip/hip_runtime.h>
#include <hip/hip_bf16.h>
#include <math.h>

// DenseGCN3Layer on MI355X — round 13.
// Changes vs r12 (agg<64> regressed 62->99µs from gather-time dinv + fat
// fused-gemm1 epilogue):
//  * g1 pre-scaling restored WITHOUT the dinv->gemm0 dependency: csr_build
//    scales g1 in place (dinv per bucket already in LDS; coalesced 25.6MB).
//  * agg<64> main loop back to r10 form (pre-scaled gathers, no dinv stream);
//    epilogue writes x1 only.
//  * gemm1 de-fused back to the r9 MFMA kernel (~6µs) — 48-wide scalar
//    matvec per node was ~2x the agg main loop at avg degree 32.
//  * Kept from r12: FKA{prep ∥ hist}, FKB{partition ∥ gemm0}, fused gemm2 in
//    agg<32> (cheap: ~20 ops/node), head in agg<16>.

#define NBUCK_MAX 512
#define P1_CHUNK 4096
#define EPT 16
#define BCAP 9216
#define PREP_BLOCKS 142
#define HIST_BLOCKS 1024

typedef __attribute__((ext_vector_type(8))) short bfrag;   // 8 bf16 (4 VGPR)
typedef __attribute__((ext_vector_type(4))) float f4_t;    // acc
typedef __attribute__((ext_vector_type(2))) float f2_t;    // packed pair

__device__ inline float uaf(unsigned u) { return __uint_as_float(u); }
__device__ inline ushort f2bf(float f) {
    __hip_bfloat16 b = __float2bfloat16(f);
    return *reinterpret_cast<ushort*>(&b);
}
__device__ inline unsigned scale2(unsigned w, float s) {
    const float lo = uaf(w << 16) * s;
    const float hi = uaf(w & 0xffff0000u) * s;
    return (unsigned)f2bf(lo) | ((unsigned)f2bf(hi) << 16);
}
__device__ inline bfrag cvt8(const float4 a, const float4 b) {
    union { ushort u[8]; bfrag f; } r;
    r.u[0] = f2bf(a.x); r.u[1] = f2bf(a.y); r.u[2] = f2bf(a.z); r.u[3] = f2bf(a.w);
    r.u[4] = f2bf(b.x); r.u[5] = f2bf(b.y); r.u[6] = f2bf(b.z); r.u[7] = f2bf(b.w);
    return r.f;
}
__device__ inline bfrag ld_bfrag(const ushort* p) {
    const uint4 raw = *reinterpret_cast<const uint4*>(p);
    return *reinterpret_cast<const bfrag*>(&raw);
}

// ------------------------------------------------ FKA: prep ∥ hist

__global__ __launch_bounds__(256) void fka_kernel(
    const float* __restrict__ W1, const float* __restrict__ Ws02,
    const float* __restrict__ Ws03, const float* __restrict__ W2,
    const float* __restrict__ Ws13, const float* __restrict__ W3,
    ushort* __restrict__ Wt0, ushort* __restrict__ Wt1, ushort* __restrict__ Wt2,
    const int* __restrict__ dst, int E, int* __restrict__ bucket_count,
    int nbuckets)
{
    if (blockIdx.x < PREP_BLOCKS) {
        const int idx = blockIdx.x * 256 + threadIdx.x;
        if (idx < 32768) {
            int f = idx >> 8, k = idx & 255;
            float v = 0.f;
            if (f < 64)       v = W1[k * 64 + f];
            else if (f < 96)  v = Ws02[k * 32 + (f - 64)];
            else if (f < 112) v = Ws03[k * 16 + (f - 96)];
            Wt0[idx] = f2bf(v);
        } else if (idx < 32768 + 3072) {
            int t = idx - 32768;
            int f = t >> 6, k = t & 63;
            float v = (f < 32) ? W2[k * 32 + f] : Ws13[k * 16 + (f - 32)];
            Wt1[t] = f2bf(v);
        } else if (idx < 32768 + 3072 + 512) {
            int t = idx - 32768 - 3072;
            int f = t >> 5, k = t & 31;
            Wt2[t] = f2bf(W3[k * 16 + f]);
        }
        return;
    }
    __shared__ int lhist[NBUCK_MAX];
    const int bid = blockIdx.x - PREP_BLOCKS;
    for (int i = threadIdx.x; i < nbuckets; i += 256) lhist[i] = 0;
    __syncthreads();
    const int stride = HIST_BLOCKS * 256;
    for (int e = bid * 256 + threadIdx.x; e < E; e += stride)
        atomicAdd(&lhist[dst[e] >> 8], 1);
    __syncthreads();
    for (int i = threadIdx.x; i < nbuckets; i += 256) {
        int c = lhist[i];
        if (c) atomicAdd(&bucket_count[i], c);
    }
}

// ------------------------------------------------ scan

__global__ __launch_bounds__(512) void bucket_scan_kernel(
    const int* __restrict__ bucket_count, int* __restrict__ bucket_base,
    int* __restrict__ bucket_cursor, int nbuckets)
{
    __shared__ int tmp[512];
    const int tid = threadIdx.x;
    int v = (tid < nbuckets) ? bucket_count[tid] : 0;
    tmp[tid] = v;
    __syncthreads();
    for (int off = 1; off < 512; off <<= 1) {
        int t = (tid >= off) ? tmp[tid - off] : 0;
        __syncthreads();
        tmp[tid] += t;
        __syncthreads();
    }
    if (tid < nbuckets) {
        int base = tmp[tid] - v;
        bucket_base[tid]   = base;
        bucket_cursor[tid] = base;
    }
}

// ------------------------------------------------ FKB: partition ∥ gemm0

union FKBsh {
    float xs[2][4096];                       // gemm0: 2 x 16 KB
    struct {
        int hist[NBUCK_MAX];
        int lofs[NBUCK_MAX];
        int gbase[NBUCK_MAX];
        int lcur[NBUCK_MAX];
        int ssum[256];
        unsigned int stage[P1_CHUNK];
        int gidx[P1_CHUNK];
    } p;                                     // partition: ~41 KB
};

__global__ __launch_bounds__(256, 3) void fkb_kernel(
    const int* __restrict__ src, const int* __restrict__ dst, int E,
    int* __restrict__ bucket_cursor, unsigned int* __restrict__ keys,
    int nbuckets, int part_blocks,
    const float* __restrict__ X, const ushort* __restrict__ Wt0,
    const float* __restrict__ bs02, const float* __restrict__ bs03,
    ushort* __restrict__ g1, float* __restrict__ pre2,
    float* __restrict__ pre3, int N)
{
    __shared__ __align__(16) FKBsh sh;
    const int tid = threadIdx.x;

    if (blockIdx.x < part_blocks) {
        const int e0 = blockIdx.x * P1_CHUNK;
        const int nE = min(P1_CHUNK, E - e0);

        for (int i = tid; i < NBUCK_MAX; i += 256) { sh.p.hist[i] = 0; sh.p.lcur[i] = 0; }
        __syncthreads();

        int myb[EPT];
        unsigned int mypk[EPT];
#pragma unroll
        for (int j = 0; j < EPT; ++j) {
            const int e = e0 + tid + j * 256;
            if (e < E) {
                const int d = dst[e];
                myb[j]  = d >> 8;
                mypk[j] = ((unsigned int)(d & 255) << 17) | (unsigned int)src[e];
                atomicAdd(&sh.p.hist[myb[j]], 1);
            } else myb[j] = -1;
        }
        __syncthreads();

        int a0 = (2 * tid     < nbuckets) ? sh.p.hist[2 * tid]     : 0;
        int a1 = (2 * tid + 1 < nbuckets) ? sh.p.hist[2 * tid + 1] : 0;
        sh.p.ssum[tid] = a0 + a1;
        __syncthreads();
        for (int off = 1; off < 256; off <<= 1) {
            int t = (tid >= off) ? sh.p.ssum[tid - off] : 0;
            __syncthreads();
            sh.p.ssum[tid] += t;
            __syncthreads();
        }
        const int ex = sh.p.ssum[tid] - (a0 + a1);
        if (2 * tid     < nbuckets) sh.p.lofs[2 * tid]     = ex;
        if (2 * tid + 1 < nbuckets) sh.p.lofs[2 * tid + 1] = ex + a0;
        __syncthreads();

        for (int i = tid; i < nbuckets; i += 256)
            sh.p.gbase[i] = atomicAdd(&bucket_cursor[i], sh.p.hist[i]);
        __syncthreads();

#pragma unroll
        for (int j = 0; j < EPT; ++j) {
            if (myb[j] >= 0) {
                const int b = myb[j];
                const int l = sh.p.lofs[b] + atomicAdd(&sh.p.lcur[b], 1);
                sh.p.stage[l] = mypk[j];
                sh.p.gidx[l]  = sh.p.gbase[b] - sh.p.lofs[b] + l;
            }
        }
        __syncthreads();

        for (int i = tid; i < nE; i += 256)
            keys[sh.p.gidx[i]] = sh.p.stage[i];
        return;
    }

    // ---------------- gemm0 role (writes UNSCALED h) ----------------
    const int bid  = blockIdx.x - part_blocks;
    const int lane = tid & 63;
    const int wf   = tid >> 6;
    const int n0   = bid * 64;
    const int mrow = lane & 15;
    const int q    = lane >> 4;
    const int kq   = q * 8;

    bfrag bfr[2][8];
#pragma unroll
    for (int ft = 0; ft < 2; ++ft) {
        const ushort* wr = &Wt0[(size_t)(wf * 32 + ft * 16 + mrow) * 256 + kq];
#pragma unroll
        for (int p = 0; p < 8; ++p)
            bfr[ft][p] = ld_bfrag(&wr[p * 32]);
    }

    int srow[4], schunk[4];
#pragma unroll
    for (int j = 0; j < 4; ++j) {
        const int R = wf * 16 + j * 4 + q;
        srow[j]   = min(n0 + R, N - 1);
        schunk[j] = mrow ^ (R & 7);
    }

    auto STAGE = [&](int buf, int kc) {
#pragma unroll
        for (int j = 0; j < 4; ++j) {
            const float* gsrc =
                X + (size_t)srow[j] * 256 + kc * 64 + schunk[j] * 4;
            __builtin_amdgcn_global_load_lds(
                (const __attribute__((address_space(1))) unsigned int*)gsrc,
                (__attribute__((address_space(3))) unsigned int*)
                    &sh.xs[buf][(wf * 16 + j * 4) * 64],
                16, 0, 0);
        }
    };

    f4_t acc[4][2];
#pragma unroll
    for (int a = 0; a < 4; ++a)
#pragma unroll
        for (int b = 0; b < 2; ++b) acc[a][b] = {0.f, 0.f, 0.f, 0.f};

    STAGE(0, 0);
    __syncthreads();

    int cur = 0;
    for (int kc = 0; kc < 4; ++kc) {
        if (kc < 3) STAGE(cur ^ 1, kc + 1);
        const float4* Xs4 = reinterpret_cast<const float4*>(&sh.xs[cur][0]);
#pragma unroll
        for (int pl = 0; pl < 2; ++pl) {
            bfrag af[4];
#pragma unroll
            for (int mt = 0; mt < 4; ++mt) {
                const int r  = mt * 16 + mrow;
                const int c0 = pl * 8 + q * 2;
                const float4 u0 = Xs4[r * 16 + (c0 ^ (r & 7))];
                const float4 u1 = Xs4[r * 16 + ((c0 + 1) ^ (r & 7))];
                af[mt] = cvt8(u0, u1);
            }
            const int pg = kc * 2 + pl;
#pragma unroll
            for (int mt = 0; mt < 4; ++mt)
#pragma unroll
                for (int ft = 0; ft < 2; ++ft)
                    acc[mt][ft] = __builtin_amdgcn_mfma_f32_16x16x32_bf16(
                        af[mt], bfr[ft][pg], acc[mt][ft], 0, 0, 0);
        }
        __syncthreads();
        cur ^= 1;
    }

    char* sm = (char*)&sh;
    ushort* g1s = (ushort*)sm;                   // [64][64]  8 KB
    float*  p2s = (float*)(sm + 8192);           // [64][32]  8 KB
    float*  p3s = (float*)(sm + 16384);          // [64][16]  4 KB

    if (wf < 2) {
#pragma unroll
        for (int mt = 0; mt < 4; ++mt) {
#pragma unroll
            for (int r = 0; r < 4; ++r) {
                const int nl = mt * 16 + q * 4 + r;
#pragma unroll
                for (int ft = 0; ft < 2; ++ft)
                    g1s[nl * 64 + wf * 32 + ft * 16 + mrow] =
                        f2bf(acc[mt][ft][r]);
            }
        }
    } else if (wf == 2) {
#pragma unroll
        for (int mt = 0; mt < 4; ++mt)
#pragma unroll
            for (int ft = 0; ft < 2; ++ft)
#pragma unroll
                for (int r = 0; r < 4; ++r)
                    p2s[(mt * 16 + q * 4 + r) * 32 + ft * 16 + mrow] =
                        acc[mt][ft][r] + bs02[ft * 16 + mrow];
    } else {
#pragma unroll
        for (int mt = 0; mt < 4; ++mt)
#pragma unroll
            for (int r = 0; r < 4; ++r)
                p3s[(mt * 16 + q * 4 + r) * 16 + mrow] =
                    acc[mt][0][r] + bs03[mrow];
    }
    __syncthreads();

    const uint4* g1v = (const uint4*)g1s;
    const uint4* p2v = (const uint4*)p2s;
    const uint4* p3v = (const uint4*)p3s;
#pragma unroll
    for (int t = 0; t < 2; ++t) {
        const int i   = t * 256 + tid;
        const int row = i >> 3;
        if (n0 + row < N)
            *(uint4*)(g1 + (size_t)(n0 + row) * 64 + (i & 7) * 8) = g1v[i];
    }
#pragma unroll
    for (int t = 0; t < 2; ++t) {
        const int i   = t * 256 + tid;
        const int row = i >> 3;
        if (n0 + row < N)
            *(uint4*)(pre2 + (size_t)(n0 + row) * 32 + (i & 7) * 4) = p2v[i];
    }
    {
        const int i   = tid;
        const int row = i >> 2;
        if (n0 + row < N)
            *(uint4*)(pre3 + (size_t)(n0 + row) * 16 + (i & 3) * 4) = p3v[i];
    }
}

// ------------------------------------------------ csr build + dinv + g1 scale

__global__ __launch_bounds__(256) void csr_build_kernel(
    const unsigned int* __restrict__ keys, const int* __restrict__ bucket_base,
    const int* __restrict__ bucket_count,
    int* __restrict__ row_off, float* __restrict__ dinv, int* __restrict__ col,
    ushort* __restrict__ g1, int N, int E)
{
    __shared__ unsigned int inb[BCAP];
    __shared__ int outv[BCAP];
    __shared__ int hist[256];
    __shared__ int lofs[256];
    __shared__ int ssum[256];
    __shared__ float sdinv[256];

    const int tid  = threadIdx.x;
    const int b    = blockIdx.x;
    const int base = bucket_base[b];
    const int cnt  = min(bucket_count[b], BCAP);
    const int n0   = b << 8;
    const int nn   = min(256, N - n0);

    for (int i = tid; i < cnt; i += 256) inb[i] = keys[base + i];
    hist[tid] = 0;
    __syncthreads();

    for (int i = tid; i < cnt; i += 256)
        atomicAdd(&hist[inb[i] >> 17], 1);
    __syncthreads();

    ssum[tid] = hist[tid];
    __syncthreads();
    for (int off = 1; off < 256; off <<= 1) {
        int t = (tid >= off) ? ssum[tid - off] : 0;
        __syncthreads();
        ssum[tid] += t;
        __syncthreads();
    }
    lofs[tid] = ssum[tid] - hist[tid];

    if (tid < nn) {
        const float dv = rsqrtf((float)hist[tid] + 1.0f);
        row_off[n0 + tid] = base + lofs[tid];
        dinv[n0 + tid]    = dv;
        sdinv[tid]        = dv;
    }
    if (b == 0 && tid == 0) row_off[N] = E;
    __syncthreads();

    // scale g1 rows of this bucket in place: g1[n] *= dinv[n]  (coalesced)
    for (int i = tid; i < nn * 8; i += 256) {
        const int row = i >> 3, ch = i & 7;
        uint4* pp = reinterpret_cast<uint4*>(g1 + (size_t)(n0 + row) * 64 + ch * 8);
        const float dv = sdinv[row];
        uint4 v = *pp;
        v.x = scale2(v.x, dv); v.y = scale2(v.y, dv);
        v.z = scale2(v.z, dv); v.w = scale2(v.w, dv);
        *pp = v;
    }

    hist[tid] = 0;
    __syncthreads();

    for (int i = tid; i < cnt; i += 256) {
        const unsigned int k = inb[i];
        const int node = k >> 17;
        const int l = lofs[node] + atomicAdd(&hist[node], 1);
        outv[l] = (int)(k & 0x1FFFF);
    }
    __syncthreads();

    for (int i = tid; i < cnt; i += 256)
        col[base + i] = outv[i];
}

// ------------------------------------------------ gemm1 (r9 version)

__global__ __launch_bounds__(256) void gemm_mfma1(
    const ushort* __restrict__ X1, const ushort* __restrict__ Wt1,
    const float* __restrict__ bs13, const float* __restrict__ dinv,
    __hip_bfloat16* __restrict__ g2, float* __restrict__ pre3, int N)
{
    __shared__ __align__(16) ushort g2s[128 * 32];   // 8 KB
    __shared__ __align__(16) float  p3s[128 * 16];   // 8 KB

    const int tid  = threadIdx.x;
    const int lane = tid & 63;
    const int wave = tid >> 6;
    const int nb   = blockIdx.x * 128;
    const int n0   = nb + wave * 32;
    const int mrow = lane & 15;
    const int q    = lane >> 4;
    const int kq   = q * 8;

    f4_t acc[2][3];
#pragma unroll
    for (int a = 0; a < 2; ++a)
#pragma unroll
        for (int b = 0; b < 3; ++b) acc[a][b] = {0.f, 0.f, 0.f, 0.f};

    const ushort* xrow[2];
#pragma unroll
    for (int mt = 0; mt < 2; ++mt) {
        int r = n0 + mt * 16 + mrow;
        r = (r < N) ? r : (N - 1);
        xrow[mt] = &X1[(size_t)r * 64 + kq];
    }
    const ushort* wrow[3];
#pragma unroll
    for (int ft = 0; ft < 3; ++ft)
        wrow[ft] = &Wt1[(size_t)(ft * 16 + mrow) * 64 + kq];

#pragma unroll
    for (int p = 0; p < 2; ++p) {
        bfrag af[2], bf[3];
#pragma unroll
        for (int mt = 0; mt < 2; ++mt) af[mt] = ld_bfrag(&xrow[mt][p * 32]);
#pragma unroll
        for (int ft = 0; ft < 3; ++ft) bf[ft] = ld_bfrag(&wrow[ft][p * 32]);
#pragma unroll
        for (int mt = 0; mt < 2; ++mt)
#pragma unroll
            for (int ft = 0; ft < 3; ++ft)
                acc[mt][ft] = __builtin_amdgcn_mfma_f32_16x16x32_bf16(
                    af[mt], bf[ft], acc[mt][ft], 0, 0, 0);
    }

#pragma unroll
    for (int mt = 0; mt < 2; ++mt) {
#pragma unroll
        for (int r = 0; r < 4; ++r) {
            const int nl = wave * 32 + mt * 16 + q * 4 + r;
            const float di = dinv[min(nb + nl, N - 1)];
            g2s[nl * 32 +      mrow] = f2bf(di * acc[mt][0][r]);
            g2s[nl * 32 + 16 + mrow] = f2bf(di * acc[mt][1][r]);
            p3s[nl * 16 + mrow] = acc[mt][2][r] + bs13[mrow];
        }
    }
    __syncthreads();

    const uint4*  g2v = (const uint4*)g2s;
    const float4* p3v = (const float4*)p3s;
#pragma unroll
    for (int t = 0; t < 2; ++t) {
        const int i   = t * 256 + tid;
        const int row = i >> 2;
        if (nb + row < N)
            *(uint4*)((ushort*)g2 + (size_t)(nb + row) * 32 + (i & 3) * 8) =
                g2v[i];
    }
#pragma unroll
    for (int t = 0; t < 2; ++t) {
        const int i   = t * 256 + tid;
        const int row = i >> 2;
        if (nb + row < N) {
            float4* dst =
                (float4*)(pre3 + (size_t)(nb + row) * 16 + (i & 3) * 4);
            float4 v = *dst;
            const float4 s = p3v[i];
            v.x += s.x; v.y += s.y; v.z += s.z; v.w += s.w;
            *dst = v;
        }
    }
}

// ---------------------------------------------------------------- aggregation
// Pre-scaled inputs for all modes (r10 main loop). Epilogues:
//   MODE 0 (F=64): self+b1, relu -> x1 bf16.
//   MODE 1 (F=32): +pre2, relu; fused gemm2 -> g3 (di-scaled), Wk=Wt2.
//   MODE 2 (F=16): +pre3, relu; output head -> sigmoid.

template<int F, int MODE>
__global__ __launch_bounds__(256) void agg_kernel(
    const ushort* __restrict__ g, const float* __restrict__ dinv,
    const int* __restrict__ row_off, const int* __restrict__ col,
    const float* __restrict__ bias, const float* __restrict__ pre,
    const ushort* __restrict__ Wk,
    const float* __restrict__ Wout, const float* __restrict__ bout,
    void* __restrict__ out, int N)
{
    constexpr int FG  = F / 8;            // lanes per edge
    constexpr int EPW = 64 / FG;          // edges in flight per wave
    constexpr int U   = 32 / EPW;         // bursts so U*EPW = 32 slots
    constexpr int LSH = (F == 64) ? 7 : (F == 32 ? 6 : 5);  // log2(row bytes)

    const int lane = threadIdx.x & 63;
    const int wv   = threadIdx.x >> 6;
    const int i    = blockIdx.x * 4 + wv;
    if (i >= N) return;

    const int fg  = lane & (FG - 1);
    const int eo  = lane / FG;
    const unsigned fbb = (unsigned)fg * 16;

    const char* gb = (const char*)g;

    f2_t acc0 = {0.f, 0.f}, acc1 = {0.f, 0.f};
    f2_t acc2 = {0.f, 0.f}, acc3 = {0.f, 0.f};

    const int s = row_off[i], e = row_off[i + 1];
    const int nfull = (e - s) >> 5;
    int p = s;
    const int* cp = col + s + eo;

    for (int it = 0; it < nfull; ++it, p += 32, cp += 32) {
        unsigned voff[U];
#pragma unroll
        for (int u = 0; u < U; ++u)
            voff[u] = ((unsigned)cp[u * EPW] << LSH) + fbb;
        uint4 w[U];
#pragma unroll
        for (int u = 0; u < U; ++u)
            w[u] = *reinterpret_cast<const uint4*>(gb + voff[u]);
#pragma unroll
        for (int u = 0; u < U; ++u) {
            acc0 += (f2_t){uaf(w[u].x << 16), uaf(w[u].x & 0xffff0000u)};
            acc1 += (f2_t){uaf(w[u].y << 16), uaf(w[u].y & 0xffff0000u)};
            acc2 += (f2_t){uaf(w[u].z << 16), uaf(w[u].z & 0xffff0000u)};
            acc3 += (f2_t){uaf(w[u].w << 16), uaf(w[u].w & 0xffff0000u)};
        }
    }
    if (p < e) {
        float m[U];
        unsigned voff[U];
#pragma unroll
        for (int u = 0; u < U; ++u) {
            const int q = p + eo + u * EPW;
            m[u]    = (q < e) ? 1.0f : 0.0f;
            voff[u] = ((unsigned)col[min(q, e - 1)] << LSH) + fbb;
        }
        uint4 w[U];
#pragma unroll
        for (int u = 0; u < U; ++u)
            w[u] = *reinterpret_cast<const uint4*>(gb + voff[u]);
#pragma unroll
        for (int u = 0; u < U; ++u) {
            const f2_t mm = {m[u], m[u]};
            acc0 += mm * (f2_t){uaf(w[u].x << 16), uaf(w[u].x & 0xffff0000u)};
            acc1 += mm * (f2_t){uaf(w[u].y << 16), uaf(w[u].y & 0xffff0000u)};
            acc2 += mm * (f2_t){uaf(w[u].z << 16), uaf(w[u].z & 0xffff0000u)};
            acc3 += mm * (f2_t){uaf(w[u].w << 16), uaf(w[u].w & 0xffff0000u)};
        }
    }

#pragma unroll
    for (int ro = FG; ro < 64; ro <<= 1) {
        acc0.x += __shfl_xor(acc0.x, ro); acc0.y += __shfl_xor(acc0.y, ro);
        acc1.x += __shfl_xor(acc1.x, ro); acc1.y += __shfl_xor(acc1.y, ro);
        acc2.x += __shfl_xor(acc2.x, ro); acc2.y += __shfl_xor(acc2.y, ro);
        acc3.x += __shfl_xor(acc3.x, ro); acc3.y += __shfl_xor(acc3.y, ro);
    }

    const uint4 ws =
        *reinterpret_cast<const uint4*>(gb + (((unsigned)i) << LSH) + fbb);
    const float di = dinv[i];
    const int fb = fg * 8;
    const float4 b0 = *reinterpret_cast<const float4*>(&bias[fb]);
    const float4 b1 = *reinterpret_cast<const float4*>(&bias[fb + 4]);

    float v0 = di * (acc0.x + uaf(ws.x << 16))         + b0.x;
    float v1 = di * (acc0.y + uaf(ws.x & 0xffff0000u)) + b0.y;
    float v2 = di * (acc1.x + uaf(ws.y << 16))         + b0.z;
    float v3 = di * (acc1.y + uaf(ws.y & 0xffff0000u)) + b0.w;
    float v4 = di * (acc2.x + uaf(ws.z << 16))         + b1.x;
    float v5 = di * (acc2.y + uaf(ws.z & 0xffff0000u)) + b1.y;
    float v6 = di * (acc3.x + uaf(ws.w << 16))         + b1.z;
    float v7 = di * (acc3.y + uaf(ws.w & 0xffff0000u)) + b1.w;

    if (MODE != 0) {
        const float4 p0 = *reinterpret_cast<const float4*>(&pre[(size_t)i * F + fb]);
        const float4 p1 = *reinterpret_cast<const float4*>(&pre[(size_t)i * F + fb + 4]);
        v0 += p0.x; v1 += p0.y; v2 += p0.z; v3 += p0.w;
        v4 += p1.x; v5 += p1.y; v6 += p1.z; v7 += p1.w;
    }
    v0 = fmaxf(v0, 0.f); v1 = fmaxf(v1, 0.f);
    v2 = fmaxf(v2, 0.f); v3 = fmaxf(v3, 0.f);
    v4 = fmaxf(v4, 0.f); v5 = fmaxf(v5, 0.f);
    v6 = fmaxf(v6, 0.f); v7 = fmaxf(v7, 0.f);

    if (MODE == 0) {
        if (lane < FG) {
            uint4 o;
            o.x = (unsigned)f2bf(v0) | ((unsigned)f2bf(v1) << 16);
            o.y = (unsigned)f2bf(v2) | ((unsigned)f2bf(v3) << 16);
            o.z = (unsigned)f2bf(v4) | ((unsigned)f2bf(v5) << 16);
            o.w = (unsigned)f2bf(v6) | ((unsigned)f2bf(v7) << 16);
            *reinterpret_cast<uint4*>((char*)out + (((size_t)i) << LSH) + fbb) = o;
        }
    } else if (MODE == 1) {
        // fused gemm2: 16 outputs; lane eo handles output eo over its 8 k's.
        const uint4 wr = *reinterpret_cast<const uint4*>(&Wk[eo * 32 + fb]);
        float sacc;
        sacc  = v0 * uaf(wr.x << 16);
        sacc += v1 * uaf(wr.x & 0xffff0000u);
        sacc += v2 * uaf(wr.y << 16);
        sacc += v3 * uaf(wr.y & 0xffff0000u);
        sacc += v4 * uaf(wr.z << 16);
        sacc += v5 * uaf(wr.z & 0xffff0000u);
        sacc += v6 * uaf(wr.w << 16);
        sacc += v7 * uaf(wr.w & 0xffff0000u);
        sacc += __shfl_xor(sacc, 1);
        sacc += __shfl_xor(sacc, 2);
        if ((lane & 3) == 0)
            ((ushort*)out)[(size_t)i * 16 + eo] = f2bf(di * sacc);
    } else {
        const float4 w0 = *reinterpret_cast<const float4*>(&Wout[fb]);
        const float4 w1 = *reinterpret_cast<const float4*>(&Wout[fb + 4]);
        float t = v0 * w0.x + v1 * w0.y + v2 * w0.z + v3 * w0.w +
                  v4 * w1.x + v5 * w1.y + v6 * w1.z + v7 * w1.w;
        t += __shfl_xor(t, 1);               // FG == 2
        if (lane == 0)
            ((float*)out)[i] = 1.0f / (1.0f + expf(-(t + bout[0])));
    }
}

// ---------------------------------------------------------------- launch

extern "C" void kernel_launch(void* const* d_in, const int* in_sizes, int n_in,
                              void* d_out, int out_size, void* d_ws, size_t ws_size,
                              hipStream_t stream)
{
    const float* x    = (const float*)d_in[0];
    const int*   edge = (const int*)d_in[1];
    const float* W1   = (const float*)d_in[2];
    const float* b1   = (const float*)d_in[3];
    const float* W2   = (const float*)d_in[4];
    const float* b2   = (const float*)d_in[5];
    const float* W3   = (const float*)d_in[6];
    const float* b3   = (const float*)d_in[7];
    const float* Ws02 = (const float*)d_in[8];
    const float* bs02 = (const float*)d_in[9];
    const float* Ws03 = (const float*)d_in[10];
    const float* bs03 = (const float*)d_in[11];
    const float* Ws13 = (const float*)d_in[12];
    const float* bs13 = (const float*)d_in[13];
    const float* Wout = (const float*)d_in[14];
    const float* bout = (const float*)d_in[15];

    const int N = in_sizes[0] / 256;
    const int E = in_sizes[1] / 2;
    const int* srcv = edge;
    const int* dstv = edge + E;
    const int nbuckets = (N + 255) >> 8;

    char* ws = (char*)d_ws;
    size_t off = 0;
    auto alloc = [&](size_t bytes) -> void* {
        void* p = ws + off;
        off += (bytes + 255) & ~(size_t)255;
        return p;
    };
    unsigned int* keys = (unsigned int*)alloc((size_t)E * 4);
    int*   col      = (int*)  alloc((size_t)E * 4);
    int*   bcount   = (int*)  alloc((size_t)NBUCK_MAX * 4);
    int*   bbase    = (int*)  alloc((size_t)NBUCK_MAX * 4);
    int*   bcursor  = (int*)  alloc((size_t)NBUCK_MAX * 4);
    int*   row_off  = (int*)  alloc((size_t)(N + 1) * 4);
    float* dinv     = (float*)alloc((size_t)N * 4);
    ushort* Wt0     = (ushort*)alloc((size_t)128 * 256 * 2);
    ushort* Wt1     = (ushort*)alloc((size_t)48 * 64 * 2);
    ushort* Wt2     = (ushort*)alloc((size_t)16 * 32 * 2);
    ushort* g1      = (ushort*)alloc((size_t)N * 64 * 2);
    ushort* x1      = (ushort*)alloc((size_t)N * 64 * 2);
    ushort* g2      = (ushort*)alloc((size_t)N * 32 * 2);
    ushort* g3      = (ushort*)alloc((size_t)N * 16 * 2);
    float* pre2     = (float*)alloc((size_t)N * 32 * 4);
    float* pre3     = (float*)alloc((size_t)N * 16 * 4);

    hipMemsetAsync(bcount, 0, (size_t)NBUCK_MAX * 4, stream);

    // FKA: weight prep ∥ bucket hist
    fka_kernel<<<PREP_BLOCKS + HIST_BLOCKS, 256, 0, stream>>>(
        W1, Ws02, Ws03, W2, Ws13, W3, Wt0, Wt1, Wt2,
        dstv, E, bcount, nbuckets);

    // scan
    bucket_scan_kernel<<<1, 512, 0, stream>>>(bcount, bbase, bcursor, nbuckets);

    // FKB: partition ∥ gemm0 (unscaled g1)
    const int PB = (E + P1_CHUNK - 1) / P1_CHUNK;
    fkb_kernel<<<PB + (N + 63) / 64, 256, 0, stream>>>(
        srcv, dstv, E, bcursor, keys, nbuckets, PB,
        x, Wt0, bs02, bs03, g1, pre2, pre3, N);

    // CSR build + dinv + scale g1 in place
    csr_build_kernel<<<nbuckets, 256, 0, stream>>>(
        keys, bbase, bcount, row_off, dinv, col, g1, N, E);

    const int ab = (N + 3) / 4;

    // layer-1 aggregate (pre-scaled g1) -> x1
    agg_kernel<64, 0><<<ab, 256, 0, stream>>>(
        g1, dinv, row_off, col, b1, nullptr, nullptr,
        nullptr, nullptr, x1, N);
    // gemm1: x1 @ Wt1 -> g2 (scaled), pre3 +=
    gemm_mfma1<<<(N + 127) / 128, 256, 0, stream>>>(
        x1, Wt1, bs13, dinv, (__hip_bfloat16*)g2, pre3, N);
    // layer-2 aggregate (+pre2) + fused gemm2 -> g3 (scaled)
    agg_kernel<32, 1><<<ab, 256, 0, stream>>>(
        g2, dinv, row_off, col, b2, pre2, Wt2,
        nullptr, nullptr, g3, N);
    // layer-3 aggregate (+pre3) + output head
    agg_kernel<16, 2><<<ab, 256, 0, stream>>>(
        g3, dinv, row_off, col, b3, pre3, nullptr,
        Wout, bout, d_out, N);
}

// Round 6
// 419.696 us; speedup vs baseline: 1.3318x; 1.0161x over previous
//
#include <hip/hip_runtime.h>
#include <hip/hip_bf16.h>
#include <math.h>

// DenseGCN3Layer on MI355X — round 14.
// Changes vs r13 (fkb fused partition∥gemm0 measured 85µs > serial sum ~60):
//  * FKB de-fused. Serial proven components, reordered:
//      memset -> fka{prep ∥ hist} -> scan -> partition(8192, r10 form) ->
//      csr_build(r10 form, dinv) -> gemm0(reads dinv, single-rounding scaled
//      g1) -> agg64 -> gemm1 -> agg32(+gemm2) -> agg16(+head).
//  * csr g1-scale pass removed (gemm0 scales directly again).
//  * Kept: fka prep∥hist fusion, fused gemm2 in agg32, fused head in agg16,
//    r10 agg main loop (memory-bound floor ~62µs for agg64).

#define NBUCK_MAX 512
#define P1_CHUNK 8192
#define EPT 32
#define BCAP 9216
#define PREP_BLOCKS 142
#define HIST_BLOCKS 1024

typedef __attribute__((ext_vector_type(8))) short bfrag;   // 8 bf16 (4 VGPR)
typedef __attribute__((ext_vector_type(4))) float f4_t;    // acc
typedef __attribute__((ext_vector_type(2))) float f2_t;    // packed pair

__device__ inline float uaf(unsigned u) { return __uint_as_float(u); }
__device__ inline ushort f2bf(float f) {
    __hip_bfloat16 b = __float2bfloat16(f);
    return *reinterpret_cast<ushort*>(&b);
}
__device__ inline bfrag cvt8(const float4 a, const float4 b) {
    union { ushort u[8]; bfrag f; } r;
    r.u[0] = f2bf(a.x); r.u[1] = f2bf(a.y); r.u[2] = f2bf(a.z); r.u[3] = f2bf(a.w);
    r.u[4] = f2bf(b.x); r.u[5] = f2bf(b.y); r.u[6] = f2bf(b.z); r.u[7] = f2bf(b.w);
    return r.f;
}
__device__ inline bfrag ld_bfrag(const ushort* p) {
    const uint4 raw = *reinterpret_cast<const uint4*>(p);
    return *reinterpret_cast<const bfrag*>(&raw);
}

// ------------------------------------------------ FKA: prep ∥ hist

__global__ __launch_bounds__(256) void fka_kernel(
    const float* __restrict__ W1, const float* __restrict__ Ws02,
    const float* __restrict__ Ws03, const float* __restrict__ W2,
    const float* __restrict__ Ws13, const float* __restrict__ W3,
    ushort* __restrict__ Wt0, ushort* __restrict__ Wt1, ushort* __restrict__ Wt2,
    const int* __restrict__ dst, int E, int* __restrict__ bucket_count,
    int nbuckets)
{
    if (blockIdx.x < PREP_BLOCKS) {
        const int idx = blockIdx.x * 256 + threadIdx.x;
        if (idx < 32768) {
            int f = idx >> 8, k = idx & 255;
            float v = 0.f;
            if (f < 64)       v = W1[k * 64 + f];
            else if (f < 96)  v = Ws02[k * 32 + (f - 64)];
            else if (f < 112) v = Ws03[k * 16 + (f - 96)];
            Wt0[idx] = f2bf(v);
        } else if (idx < 32768 + 3072) {
            int t = idx - 32768;
            int f = t >> 6, k = t & 63;
            float v = (f < 32) ? W2[k * 32 + f] : Ws13[k * 16 + (f - 32)];
            Wt1[t] = f2bf(v);
        } else if (idx < 32768 + 3072 + 512) {
            int t = idx - 32768 - 3072;
            int f = t >> 5, k = t & 31;
            Wt2[t] = f2bf(W3[k * 16 + f]);
        }
        return;
    }
    __shared__ int lhist[NBUCK_MAX];
    const int bid = blockIdx.x - PREP_BLOCKS;
    for (int i = threadIdx.x; i < nbuckets; i += 256) lhist[i] = 0;
    __syncthreads();
    const int stride = HIST_BLOCKS * 256;
    for (int e = bid * 256 + threadIdx.x; e < E; e += stride)
        atomicAdd(&lhist[dst[e] >> 8], 1);
    __syncthreads();
    for (int i = threadIdx.x; i < nbuckets; i += 256) {
        int c = lhist[i];
        if (c) atomicAdd(&bucket_count[i], c);
    }
}

// ------------------------------------------------ scan

__global__ __launch_bounds__(512) void bucket_scan_kernel(
    const int* __restrict__ bucket_count, int* __restrict__ bucket_base,
    int* __restrict__ bucket_cursor, int nbuckets)
{
    __shared__ int tmp[512];
    const int tid = threadIdx.x;
    int v = (tid < nbuckets) ? bucket_count[tid] : 0;
    tmp[tid] = v;
    __syncthreads();
    for (int off = 1; off < 512; off <<= 1) {
        int t = (tid >= off) ? tmp[tid - off] : 0;
        __syncthreads();
        tmp[tid] += t;
        __syncthreads();
    }
    if (tid < nbuckets) {
        int base = tmp[tid] - v;
        bucket_base[tid]   = base;
        bucket_cursor[tid] = base;
    }
}

// ------------------------------------------------ partition (r10 form)

__global__ __launch_bounds__(256) void partition_kernel(
    const int* __restrict__ src, const int* __restrict__ dst, int E,
    int* __restrict__ bucket_cursor, unsigned int* __restrict__ keys, int nbuckets)
{
    __shared__ int hist[NBUCK_MAX];
    __shared__ int lofs[NBUCK_MAX];
    __shared__ int gbase[NBUCK_MAX];
    __shared__ int lcur[NBUCK_MAX];
    __shared__ int ssum[256];
    __shared__ unsigned int stage[P1_CHUNK];
    __shared__ int gidx[P1_CHUNK];

    const int tid = threadIdx.x;
    const int e0  = blockIdx.x * P1_CHUNK;
    const int nE  = min(P1_CHUNK, E - e0);

    for (int i = tid; i < NBUCK_MAX; i += 256) { hist[i] = 0; lcur[i] = 0; }
    __syncthreads();

    int myb[EPT];
    unsigned int mypk[EPT];
#pragma unroll
    for (int j = 0; j < EPT; ++j) {
        const int e = e0 + tid + j * 256;
        if (e < E) {
            const int d = dst[e];
            myb[j]  = d >> 8;
            mypk[j] = ((unsigned int)(d & 255) << 17) | (unsigned int)src[e];
            atomicAdd(&hist[myb[j]], 1);
        } else myb[j] = -1;
    }
    __syncthreads();

    int a0 = (2 * tid     < nbuckets) ? hist[2 * tid]     : 0;
    int a1 = (2 * tid + 1 < nbuckets) ? hist[2 * tid + 1] : 0;
    ssum[tid] = a0 + a1;
    __syncthreads();
    for (int off = 1; off < 256; off <<= 1) {
        int t = (tid >= off) ? ssum[tid - off] : 0;
        __syncthreads();
        ssum[tid] += t;
        __syncthreads();
    }
    const int ex = ssum[tid] - (a0 + a1);
    if (2 * tid     < nbuckets) lofs[2 * tid]     = ex;
    if (2 * tid + 1 < nbuckets) lofs[2 * tid + 1] = ex + a0;
    __syncthreads();

    for (int i = tid; i < nbuckets; i += 256)
        gbase[i] = atomicAdd(&bucket_cursor[i], hist[i]);
    __syncthreads();

#pragma unroll
    for (int j = 0; j < EPT; ++j) {
        if (myb[j] >= 0) {
            const int b = myb[j];
            const int l = lofs[b] + atomicAdd(&lcur[b], 1);
            stage[l] = mypk[j];
            gidx[l]  = gbase[b] - lofs[b] + l;
        }
    }
    __syncthreads();

    for (int i = tid; i < nE; i += 256)
        keys[gidx[i]] = stage[i];
}

// ------------------------------------------------ csr build + dinv (r10 form)

__global__ __launch_bounds__(256) void csr_build_kernel(
    const unsigned int* __restrict__ keys, const int* __restrict__ bucket_base,
    const int* __restrict__ bucket_count,
    int* __restrict__ row_off, float* __restrict__ dinv, int* __restrict__ col,
    int N, int E)
{
    __shared__ unsigned int inb[BCAP];
    __shared__ int outv[BCAP];
    __shared__ int hist[256];
    __shared__ int lofs[256];
    __shared__ int ssum[256];

    const int tid  = threadIdx.x;
    const int b    = blockIdx.x;
    const int base = bucket_base[b];
    const int cnt  = min(bucket_count[b], BCAP);
    const int n0   = b << 8;
    const int nn   = min(256, N - n0);

    for (int i = tid; i < cnt; i += 256) inb[i] = keys[base + i];
    hist[tid] = 0;
    __syncthreads();

    for (int i = tid; i < cnt; i += 256)
        atomicAdd(&hist[inb[i] >> 17], 1);
    __syncthreads();

    ssum[tid] = hist[tid];
    __syncthreads();
    for (int off = 1; off < 256; off <<= 1) {
        int t = (tid >= off) ? ssum[tid - off] : 0;
        __syncthreads();
        ssum[tid] += t;
        __syncthreads();
    }
    lofs[tid] = ssum[tid] - hist[tid];

    if (tid < nn) {
        row_off[n0 + tid] = base + lofs[tid];
        dinv[n0 + tid]    = rsqrtf((float)hist[tid] + 1.0f);
    }
    if (b == 0 && tid == 0) row_off[N] = E;
    __syncthreads();

    hist[tid] = 0;
    __syncthreads();

    for (int i = tid; i < cnt; i += 256) {
        const unsigned int k = inb[i];
        const int node = k >> 17;
        const int l = lofs[node] + atomicAdd(&hist[node], 1);
        outv[l] = (int)(k & 0x1FFFF);
    }
    __syncthreads();

    for (int i = tid; i < cnt; i += 256)
        col[base + i] = outv[i];
}

// ------------------------------------------------ gemm0 (r10 form, scaled g1)

__global__ __launch_bounds__(256, 3) void gemm_mfma0(
    const float* __restrict__ X, const ushort* __restrict__ Wt0,
    const float* __restrict__ bs02, const float* __restrict__ bs03,
    const float* __restrict__ dinv,
    ushort* __restrict__ g1, float* __restrict__ pre2,
    float* __restrict__ pre3, int N)
{
    __shared__ __align__(16) float Xs[2][64 * 64];   // 2 x 16 KB, chunk-swizzled

    const int tid  = threadIdx.x;
    const int lane = tid & 63;
    const int wf   = tid >> 6;
    const int n0   = blockIdx.x * 64;
    const int mrow = lane & 15;
    const int q    = lane >> 4;
    const int kq   = q * 8;

    bfrag bfr[2][8];
#pragma unroll
    for (int ft = 0; ft < 2; ++ft) {
        const ushort* wr = &Wt0[(size_t)(wf * 32 + ft * 16 + mrow) * 256 + kq];
#pragma unroll
        for (int p = 0; p < 8; ++p)
            bfr[ft][p] = ld_bfrag(&wr[p * 32]);
    }

    int srow[4], schunk[4];
#pragma unroll
    for (int j = 0; j < 4; ++j) {
        const int R = wf * 16 + j * 4 + q;
        srow[j]   = min(n0 + R, N - 1);
        schunk[j] = mrow ^ (R & 7);
    }

    auto STAGE = [&](int buf, int kc) {
#pragma unroll
        for (int j = 0; j < 4; ++j) {
            const float* gsrc =
                X + (size_t)srow[j] * 256 + kc * 64 + schunk[j] * 4;
            __builtin_amdgcn_global_load_lds(
                (const __attribute__((address_space(1))) unsigned int*)gsrc,
                (__attribute__((address_space(3))) unsigned int*)
                    &Xs[buf][(wf * 16 + j * 4) * 64],
                16, 0, 0);
        }
    };

    f4_t acc[4][2];
#pragma unroll
    for (int a = 0; a < 4; ++a)
#pragma unroll
        for (int b = 0; b < 2; ++b) acc[a][b] = {0.f, 0.f, 0.f, 0.f};

    STAGE(0, 0);
    __syncthreads();

    int cur = 0;
    for (int kc = 0; kc < 4; ++kc) {
        if (kc < 3) STAGE(cur ^ 1, kc + 1);
        const float4* Xs4 = reinterpret_cast<const float4*>(&Xs[cur][0]);
#pragma unroll
        for (int pl = 0; pl < 2; ++pl) {
            bfrag af[4];
#pragma unroll
            for (int mt = 0; mt < 4; ++mt) {
                const int r  = mt * 16 + mrow;
                const int c0 = pl * 8 + q * 2;
                const float4 u0 = Xs4[r * 16 + (c0 ^ (r & 7))];
                const float4 u1 = Xs4[r * 16 + ((c0 + 1) ^ (r & 7))];
                af[mt] = cvt8(u0, u1);
            }
            const int pg = kc * 2 + pl;
#pragma unroll
            for (int mt = 0; mt < 4; ++mt)
#pragma unroll
                for (int ft = 0; ft < 2; ++ft)
                    acc[mt][ft] = __builtin_amdgcn_mfma_f32_16x16x32_bf16(
                        af[mt], bfr[ft][pg], acc[mt][ft], 0, 0, 0);
        }
        __syncthreads();
        cur ^= 1;
    }

    // staged epilogue (reuses Xs)
    char* sm = (char*)Xs;
    ushort* g1s = (ushort*)sm;                   // [64][64]  8 KB
    float*  p2s = (float*)(sm + 8192);           // [64][32]  8 KB
    float*  p3s = (float*)(sm + 16384);          // [64][16]  4 KB

    if (wf < 2) {
#pragma unroll
        for (int mt = 0; mt < 4; ++mt) {
#pragma unroll
            for (int r = 0; r < 4; ++r) {
                const int nl = mt * 16 + q * 4 + r;
                const float di = dinv[min(n0 + nl, N - 1)];
#pragma unroll
                for (int ft = 0; ft < 2; ++ft)
                    g1s[nl * 64 + wf * 32 + ft * 16 + mrow] =
                        f2bf(di * acc[mt][ft][r]);
            }
        }
    } else if (wf == 2) {
#pragma unroll
        for (int mt = 0; mt < 4; ++mt)
#pragma unroll
            for (int ft = 0; ft < 2; ++ft)
#pragma unroll
                for (int r = 0; r < 4; ++r)
                    p2s[(mt * 16 + q * 4 + r) * 32 + ft * 16 + mrow] =
                        acc[mt][ft][r] + bs02[ft * 16 + mrow];
    } else {
#pragma unroll
        for (int mt = 0; mt < 4; ++mt)
#pragma unroll
            for (int r = 0; r < 4; ++r)
                p3s[(mt * 16 + q * 4 + r) * 16 + mrow] =
                    acc[mt][0][r] + bs03[mrow];
    }
    __syncthreads();

    const uint4* g1v = (const uint4*)g1s;
    const uint4* p2v = (const uint4*)p2s;
    const uint4* p3v = (const uint4*)p3s;
#pragma unroll
    for (int t = 0; t < 2; ++t) {
        const int i   = t * 256 + tid;
        const int row = i >> 3;
        if (n0 + row < N)
            *(uint4*)(g1 + (size_t)(n0 + row) * 64 + (i & 7) * 8) = g1v[i];
    }
#pragma unroll
    for (int t = 0; t < 2; ++t) {
        const int i   = t * 256 + tid;
        const int row = i >> 3;
        if (n0 + row < N)
            *(uint4*)(pre2 + (size_t)(n0 + row) * 32 + (i & 7) * 4) = p2v[i];
    }
    {
        const int i   = tid;
        const int row = i >> 2;
        if (n0 + row < N)
            *(uint4*)(pre3 + (size_t)(n0 + row) * 16 + (i & 3) * 4) = p3v[i];
    }
}

// ------------------------------------------------ gemm1 (r9 form)

__global__ __launch_bounds__(256) void gemm_mfma1(
    const ushort* __restrict__ X1, const ushort* __restrict__ Wt1,
    const float* __restrict__ bs13, const float* __restrict__ dinv,
    __hip_bfloat16* __restrict__ g2, float* __restrict__ pre3, int N)
{
    __shared__ __align__(16) ushort g2s[128 * 32];   // 8 KB
    __shared__ __align__(16) float  p3s[128 * 16];   // 8 KB

    const int tid  = threadIdx.x;
    const int lane = tid & 63;
    const int wave = tid >> 6;
    const int nb   = blockIdx.x * 128;
    const int n0   = nb + wave * 32;
    const int mrow = lane & 15;
    const int q    = lane >> 4;
    const int kq   = q * 8;

    f4_t acc[2][3];
#pragma unroll
    for (int a = 0; a < 2; ++a)
#pragma unroll
        for (int b = 0; b < 3; ++b) acc[a][b] = {0.f, 0.f, 0.f, 0.f};

    const ushort* xrow[2];
#pragma unroll
    for (int mt = 0; mt < 2; ++mt) {
        int r = n0 + mt * 16 + mrow;
        r = (r < N) ? r : (N - 1);
        xrow[mt] = &X1[(size_t)r * 64 + kq];
    }
    const ushort* wrow[3];
#pragma unroll
    for (int ft = 0; ft < 3; ++ft)
        wrow[ft] = &Wt1[(size_t)(ft * 16 + mrow) * 64 + kq];

#pragma unroll
    for (int p = 0; p < 2; ++p) {
        bfrag af[2], bf[3];
#pragma unroll
        for (int mt = 0; mt < 2; ++mt) af[mt] = ld_bfrag(&xrow[mt][p * 32]);
#pragma unroll
        for (int ft = 0; ft < 3; ++ft) bf[ft] = ld_bfrag(&wrow[ft][p * 32]);
#pragma unroll
        for (int mt = 0; mt < 2; ++mt)
#pragma unroll
            for (int ft = 0; ft < 3; ++ft)
                acc[mt][ft] = __builtin_amdgcn_mfma_f32_16x16x32_bf16(
                    af[mt], bf[ft], acc[mt][ft], 0, 0, 0);
    }

#pragma unroll
    for (int mt = 0; mt < 2; ++mt) {
#pragma unroll
        for (int r = 0; r < 4; ++r) {
            const int nl = wave * 32 + mt * 16 + q * 4 + r;
            const float di = dinv[min(nb + nl, N - 1)];
            g2s[nl * 32 +      mrow] = f2bf(di * acc[mt][0][r]);
            g2s[nl * 32 + 16 + mrow] = f2bf(di * acc[mt][1][r]);
            p3s[nl * 16 + mrow] = acc[mt][2][r] + bs13[mrow];
        }
    }
    __syncthreads();

    const uint4*  g2v = (const uint4*)g2s;
    const float4* p3v = (const float4*)p3s;
#pragma unroll
    for (int t = 0; t < 2; ++t) {
        const int i   = t * 256 + tid;
        const int row = i >> 2;
        if (nb + row < N)
            *(uint4*)((ushort*)g2 + (size_t)(nb + row) * 32 + (i & 3) * 8) =
                g2v[i];
    }
#pragma unroll
    for (int t = 0; t < 2; ++t) {
        const int i   = t * 256 + tid;
        const int row = i >> 2;
        if (nb + row < N) {
            float4* dst =
                (float4*)(pre3 + (size_t)(nb + row) * 16 + (i & 3) * 4);
            float4 v = *dst;
            const float4 s = p3v[i];
            v.x += s.x; v.y += s.y; v.z += s.z; v.w += s.w;
            *dst = v;
        }
    }
}

// ---------------------------------------------------------------- aggregation
// Pre-scaled inputs (r10 main loop). Epilogues:
//   MODE 0 (F=64): self+b1, relu -> x1 bf16.
//   MODE 1 (F=32): +pre2, relu; fused gemm2 -> g3 (di-scaled), Wk=Wt2.
//   MODE 2 (F=16): +pre3, relu; output head -> sigmoid.

template<int F, int MODE>
__global__ __launch_bounds__(256) void agg_kernel(
    const ushort* __restrict__ g, const float* __restrict__ dinv,
    const int* __restrict__ row_off, const int* __restrict__ col,
    const float* __restrict__ bias, const float* __restrict__ pre,
    const ushort* __restrict__ Wk,
    const float* __restrict__ Wout, const float* __restrict__ bout,
    void* __restrict__ out, int N)
{
    constexpr int FG  = F / 8;            // lanes per edge
    constexpr int EPW = 64 / FG;          // edges in flight per wave
    constexpr int U   = 32 / EPW;         // bursts so U*EPW = 32 slots
    constexpr int LSH = (F == 64) ? 7 : (F == 32 ? 6 : 5);  // log2(row bytes)

    const int lane = threadIdx.x & 63;
    const int wv   = threadIdx.x >> 6;
    const int i    = blockIdx.x * 4 + wv;
    if (i >= N) return;

    const int fg  = lane & (FG - 1);
    const int eo  = lane / FG;
    const unsigned fbb = (unsigned)fg * 16;

    const char* gb = (const char*)g;

    f2_t acc0 = {0.f, 0.f}, acc1 = {0.f, 0.f};
    f2_t acc2 = {0.f, 0.f}, acc3 = {0.f, 0.f};

    const int s = row_off[i], e = row_off[i + 1];
    const int nfull = (e - s) >> 5;
    int p = s;
    const int* cp = col + s + eo;

    for (int it = 0; it < nfull; ++it, p += 32, cp += 32) {
        unsigned voff[U];
#pragma unroll
        for (int u = 0; u < U; ++u)
            voff[u] = ((unsigned)cp[u * EPW] << LSH) + fbb;
        uint4 w[U];
#pragma unroll
        for (int u = 0; u < U; ++u)
            w[u] = *reinterpret_cast<const uint4*>(gb + voff[u]);
#pragma unroll
        for (int u = 0; u < U; ++u) {
            acc0 += (f2_t){uaf(w[u].x << 16), uaf(w[u].x & 0xffff0000u)};
            acc1 += (f2_t){uaf(w[u].y << 16), uaf(w[u].y & 0xffff0000u)};
            acc2 += (f2_t){uaf(w[u].z << 16), uaf(w[u].z & 0xffff0000u)};
            acc3 += (f2_t){uaf(w[u].w << 16), uaf(w[u].w & 0xffff0000u)};
        }
    }
    if (p < e) {
        float m[U];
        unsigned voff[U];
#pragma unroll
        for (int u = 0; u < U; ++u) {
            const int q = p + eo + u * EPW;
            m[u]    = (q < e) ? 1.0f : 0.0f;
            voff[u] = ((unsigned)col[min(q, e - 1)] << LSH) + fbb;
        }
        uint4 w[U];
#pragma unroll
        for (int u = 0; u < U; ++u)
            w[u] = *reinterpret_cast<const uint4*>(gb + voff[u]);
#pragma unroll
        for (int u = 0; u < U; ++u) {
            const f2_t mm = {m[u], m[u]};
            acc0 += mm * (f2_t){uaf(w[u].x << 16), uaf(w[u].x & 0xffff0000u)};
            acc1 += mm * (f2_t){uaf(w[u].y << 16), uaf(w[u].y & 0xffff0000u)};
            acc2 += mm * (f2_t){uaf(w[u].z << 16), uaf(w[u].z & 0xffff0000u)};
            acc3 += mm * (f2_t){uaf(w[u].w << 16), uaf(w[u].w & 0xffff0000u)};
        }
    }

#pragma unroll
    for (int ro = FG; ro < 64; ro <<= 1) {
        acc0.x += __shfl_xor(acc0.x, ro); acc0.y += __shfl_xor(acc0.y, ro);
        acc1.x += __shfl_xor(acc1.x, ro); acc1.y += __shfl_xor(acc1.y, ro);
        acc2.x += __shfl_xor(acc2.x, ro); acc2.y += __shfl_xor(acc2.y, ro);
        acc3.x += __shfl_xor(acc3.x, ro); acc3.y += __shfl_xor(acc3.y, ro);
    }

    const uint4 ws =
        *reinterpret_cast<const uint4*>(gb + (((unsigned)i) << LSH) + fbb);
    const float di = dinv[i];
    const int fb = fg * 8;
    const float4 b0 = *reinterpret_cast<const float4*>(&bias[fb]);
    const float4 b1 = *reinterpret_cast<const float4*>(&bias[fb + 4]);

    float v0 = di * (acc0.x + uaf(ws.x << 16))         + b0.x;
    float v1 = di * (acc0.y + uaf(ws.x & 0xffff0000u)) + b0.y;
    float v2 = di * (acc1.x + uaf(ws.y << 16))         + b0.z;
    float v3 = di * (acc1.y + uaf(ws.y & 0xffff0000u)) + b0.w;
    float v4 = di * (acc2.x + uaf(ws.z << 16))         + b1.x;
    float v5 = di * (acc2.y + uaf(ws.z & 0xffff0000u)) + b1.y;
    float v6 = di * (acc3.x + uaf(ws.w << 16))         + b1.z;
    float v7 = di * (acc3.y + uaf(ws.w & 0xffff0000u)) + b1.w;

    if (MODE != 0) {
        const float4 p0 = *reinterpret_cast<const float4*>(&pre[(size_t)i * F + fb]);
        const float4 p1 = *reinterpret_cast<const float4*>(&pre[(size_t)i * F + fb + 4]);
        v0 += p0.x; v1 += p0.y; v2 += p0.z; v3 += p0.w;
        v4 += p1.x; v5 += p1.y; v6 += p1.z; v7 += p1.w;
    }
    v0 = fmaxf(v0, 0.f); v1 = fmaxf(v1, 0.f);
    v2 = fmaxf(v2, 0.f); v3 = fmaxf(v3, 0.f);
    v4 = fmaxf(v4, 0.f); v5 = fmaxf(v5, 0.f);
    v6 = fmaxf(v6, 0.f); v7 = fmaxf(v7, 0.f);

    if (MODE == 0) {
        if (lane < FG) {
            uint4 o;
            o.x = (unsigned)f2bf(v0) | ((unsigned)f2bf(v1) << 16);
            o.y = (unsigned)f2bf(v2) | ((unsigned)f2bf(v3) << 16);
            o.z = (unsigned)f2bf(v4) | ((unsigned)f2bf(v5) << 16);
            o.w = (unsigned)f2bf(v6) | ((unsigned)f2bf(v7) << 16);
            *reinterpret_cast<uint4*>((char*)out + (((size_t)i) << LSH) + fbb) = o;
        }
    } else if (MODE == 1) {
        // fused gemm2: 16 outputs; lane eo handles output eo over its 8 k's.
        const uint4 wr = *reinterpret_cast<const uint4*>(&Wk[eo * 32 + fb]);
        float sacc;
        sacc  = v0 * uaf(wr.x << 16);
        sacc += v1 * uaf(wr.x & 0xffff0000u);
        sacc += v2 * uaf(wr.y << 16);
        sacc += v3 * uaf(wr.y & 0xffff0000u);
        sacc += v4 * uaf(wr.z << 16);
        sacc += v5 * uaf(wr.z & 0xffff0000u);
        sacc += v6 * uaf(wr.w << 16);
        sacc += v7 * uaf(wr.w & 0xffff0000u);
        sacc += __shfl_xor(sacc, 1);
        sacc += __shfl_xor(sacc, 2);
        if ((lane & 3) == 0)
            ((ushort*)out)[(size_t)i * 16 + eo] = f2bf(di * sacc);
    } else {
        const float4 w0 = *reinterpret_cast<const float4*>(&Wout[fb]);
        const float4 w1 = *reinterpret_cast<const float4*>(&Wout[fb + 4]);
        float t = v0 * w0.x + v1 * w0.y + v2 * w0.z + v3 * w0.w +
                  v4 * w1.x + v5 * w1.y + v6 * w1.z + v7 * w1.w;
        t += __shfl_xor(t, 1);               // FG == 2
        if (lane == 0)
            ((float*)out)[i] = 1.0f / (1.0f + expf(-(t + bout[0])));
    }
}

// ---------------------------------------------------------------- launch

extern "C" void kernel_launch(void* const* d_in, const int* in_sizes, int n_in,
                              void* d_out, int out_size, void* d_ws, size_t ws_size,
                              hipStream_t stream)
{
    const float* x    = (const float*)d_in[0];
    const int*   edge = (const int*)d_in[1];
    const float* W1   = (const float*)d_in[2];
    const float* b1   = (const float*)d_in[3];
    const float* W2   = (const float*)d_in[4];
    const float* b2   = (const float*)d_in[5];
    const float* W3   = (const float*)d_in[6];
    const float* b3   = (const float*)d_in[7];
    const float* Ws02 = (const float*)d_in[8];
    const float* bs02 = (const float*)d_in[9];
    const float* Ws03 = (const float*)d_in[10];
    const float* bs03 = (const float*)d_in[11];
    const float* Ws13 = (const float*)d_in[12];
    const float* bs13 = (const float*)d_in[13];
    const float* Wout = (const float*)d_in[14];
    const float* bout = (const float*)d_in[15];

    const int N = in_sizes[0] / 256;
    const int E = in_sizes[1] / 2;
    const int* srcv = edge;
    const int* dstv = edge + E;
    const int nbuckets = (N + 255) >> 8;

    char* ws = (char*)d_ws;
    size_t off = 0;
    auto alloc = [&](size_t bytes) -> void* {
        void* p = ws + off;
        off += (bytes + 255) & ~(size_t)255;
        return p;
    };
    unsigned int* keys = (unsigned int*)alloc((size_t)E * 4);
    int*   col      = (int*)  alloc((size_t)E * 4);
    int*   bcount   = (int*)  alloc((size_t)NBUCK_MAX * 4);
    int*   bbase    = (int*)  alloc((size_t)NBUCK_MAX * 4);
    int*   bcursor  = (int*)  alloc((size_t)NBUCK_MAX * 4);
    int*   row_off  = (int*)  alloc((size_t)(N + 1) * 4);
    float* dinv     = (float*)alloc((size_t)N * 4);
    ushort* Wt0     = (ushort*)alloc((size_t)128 * 256 * 2);
    ushort* Wt1     = (ushort*)alloc((size_t)48 * 64 * 2);
    ushort* Wt2     = (ushort*)alloc((size_t)16 * 32 * 2);
    ushort* g1      = (ushort*)alloc((size_t)N * 64 * 2);
    ushort* x1      = (ushort*)alloc((size_t)N * 64 * 2);
    ushort* g2      = (ushort*)alloc((size_t)N * 32 * 2);
    ushort* g3      = (ushort*)alloc((size_t)N * 16 * 2);
    float* pre2     = (float*)alloc((size_t)N * 32 * 4);
    float* pre3     = (float*)alloc((size_t)N * 16 * 4);

    hipMemsetAsync(bcount, 0, (size_t)NBUCK_MAX * 4, stream);

    // FKA: weight prep ∥ bucket hist
    fka_kernel<<<PREP_BLOCKS + HIST_BLOCKS, 256, 0, stream>>>(
        W1, Ws02, Ws03, W2, Ws13, W3, Wt0, Wt1, Wt2,
        dstv, E, bcount, nbuckets);

    // scan
    bucket_scan_kernel<<<1, 512, 0, stream>>>(bcount, bbase, bcursor, nbuckets);

    // partition (standalone, chunk 8192)
    partition_kernel<<<(E + P1_CHUNK - 1) / P1_CHUNK, 256, 0, stream>>>(
        srcv, dstv, E, bcursor, keys, nbuckets);

    // CSR build + dinv
    csr_build_kernel<<<nbuckets, 256, 0, stream>>>(
        keys, bbase, bcount, row_off, dinv, col, N, E);

    // gemm0 (after csr: reads dinv, writes scaled g1 in one rounding)
    gemm_mfma0<<<(N + 63) / 64, 256, 0, stream>>>(
        x, Wt0, bs02, bs03, dinv, g1, pre2, pre3, N);

    const int ab = (N + 3) / 4;

    // layer-1 aggregate -> x1
    agg_kernel<64, 0><<<ab, 256, 0, stream>>>(
        g1, dinv, row_off, col, b1, nullptr, nullptr,
        nullptr, nullptr, x1, N);
    // gemm1: x1 @ Wt1 -> g2 (scaled), pre3 +=
    gemm_mfma1<<<(N + 127) / 128, 256, 0, stream>>>(
        x1, Wt1, bs13, dinv, (__hip_bfloat16*)g2, pre3, N);
    // layer-2 aggregate (+pre2) + fused gemm2 -> g3 (scaled)
    agg_kernel<32, 1><<<ab, 256, 0, stream>>>(
        g2, dinv, row_off, col, b2, pre2, Wt2,
        nullptr, nullptr, g3, N);
    // layer-3 aggregate (+pre3) + output head
    agg_kernel<16, 2><<<ab, 256, 0, stream>>>(
        g3, dinv, row_off, col, b3, pre3, nullptr,
        Wout, bout, d_out, N);
}